// Round 2
// baseline (921.676 us; speedup 1.0000x reference)
//
#include <hip/hip_runtime.h>

#define N_NODES 100000
#define N_EDGES 1200000
#define LAYERS 4
#define SLOPE 0.01f

#define NPAIR (N_NODES / 2)                 // 50000 node pairs (N even)

#define SCAN_ELEMS 1024                     // elems per scan1 block (256 thr x 4)
#define NB1 ((N_NODES + SCAN_ELEMS - 1) / SCAN_ELEMS)   // 98

// edge bucketing: 8 block-groups (XCD heuristic) x 782 dst-buckets (128 nodes each)
#define BUCKET_SHIFT 7
#define NB2 ((N_NODES + 127) >> 7)          // 782
#define NGRP 8
#define NBG (NB2 * NGRP)                    // 6256

__device__ __forceinline__ float leaky(float v) { return v >= 0.f ? v : SLOPE * v; }

#define ACC16(h, v, a, b, c, d) \
    h[0]  += v * a.x; h[1]  += v * a.y; h[2]  += v * a.z; h[3]  += v * a.w; \
    h[4]  += v * b.x; h[5]  += v * b.y; h[6]  += v * b.z; h[7]  += v * b.w; \
    h[8]  += v * c.x; h[9]  += v * c.y; h[10] += v * c.z; h[11] += v * c.w; \
    h[12] += v * d.x; h[13] += v * d.y; h[14] += v * d.z; h[15] += v * d.w;

#define ACC8(r, v, a, b) \
    r[0] += v * a.x; r[1] += v * a.y; r[2] += v * a.z; r[3] += v * a.w; \
    r[4] += v * b.x; r[5] += v * b.y; r[6] += v * b.z; r[7] += v * b.w;

// ---------------------------------------------------------------------------
// CSR build (counting sort by edge_dst, bucketed to kill write amplification)
// ---------------------------------------------------------------------------
__global__ __launch_bounds__(256) void zero_counts(
    int* __restrict__ counts, int* __restrict__ bcnt)
{
    int i = blockIdx.x * 256 + threadIdx.x;
    if (i < N_NODES) counts[i] = 0;
    if (i < NBG) bcnt[i] = 0;
}

__global__ __launch_bounds__(256) void hist_kernel(
    const int* __restrict__ dst, int* __restrict__ counts, int* __restrict__ bcnt)
{
    int e = blockIdx.x * 256 + threadIdx.x;
    if (e >= N_EDGES) return;
    int d = dst[e];
    atomicAdd(&counts[d], 1);
    atomicAdd(&bcnt[(blockIdx.x & 7) * NB2 + (d >> BUCKET_SHIFT)], 1);
}

__global__ __launch_bounds__(256) void scan1_kernel(
    const int* __restrict__ counts, int* __restrict__ offs, int* __restrict__ bsum)
{
    __shared__ int s[256];
    int b = blockIdx.x, t = threadIdx.x;
    int base = b * SCAN_ELEMS;
    int v[4]; int sum = 0;
    #pragma unroll
    for (int u = 0; u < 4; u++) {
        int idx = base + t * 4 + u;
        int c = (idx < N_NODES) ? counts[idx] : 0;
        v[u] = sum; sum += c;
    }
    s[t] = sum; __syncthreads();
    for (int off = 1; off < 256; off <<= 1) {
        int y = (t >= off) ? s[t - off] : 0;
        __syncthreads();
        s[t] += y;
        __syncthreads();
    }
    int excl = s[t] - sum;
    #pragma unroll
    for (int u = 0; u < 4; u++) {
        int idx = base + t * 4 + u;
        if (idx < N_NODES) offs[idx] = excl + v[u];
    }
    if (t == 255) bsum[b] = s[255];
}

__global__ __launch_bounds__(128) void scan2_kernel(
    const int* __restrict__ bsum, int* __restrict__ bscan)
{
    __shared__ int s[128];
    int t = threadIdx.x;
    int c = (t < NB1) ? bsum[t] : 0;
    s[t] = c; __syncthreads();
    for (int off = 1; off < 128; off <<= 1) {
        int y = (t >= off) ? s[t - off] : 0;
        __syncthreads();
        s[t] += y;
        __syncthreads();
    }
    if (t < NB1) bscan[t] = s[t] - c;
}

__global__ __launch_bounds__(256) void scan3_kernel(
    int* __restrict__ offs, int* __restrict__ cursor, const int* __restrict__ bscan)
{
    int b = blockIdx.x, t = threadIdx.x;
    int base = b * SCAN_ELEMS;
    int add = bscan[b];
    #pragma unroll
    for (int u = 0; u < 4; u++) {
        int idx = base + t * 4 + u;
        if (idx < N_NODES) {
            int v = offs[idx] + add;
            offs[idx] = v;
            cursor[idx] = v;
        }
    }
    if (b == 0 && t == 0) offs[N_NODES] = N_EDGES;
}

// exclusive scan of the 6256 (group,bucket) counts; writes offsets + cursor copy
__global__ __launch_bounds__(256) void bucket_scan(
    const int* __restrict__ bcnt, int* __restrict__ boffs, int* __restrict__ bcur)
{
    __shared__ int s[256];
    int t = threadIdx.x;
    int beg = t * 25;
    int end = beg + 25; if (end > NBG) end = NBG;
    int sum = 0;
    for (int i = beg; i < end; i++) sum += bcnt[i];
    s[t] = sum; __syncthreads();
    for (int off = 1; off < 256; off <<= 1) {
        int y = (t >= off) ? s[t - off] : 0;
        __syncthreads();
        s[t] += y;
        __syncthreads();
    }
    int excl = s[t] - sum;
    for (int i = beg; i < end; i++) {
        int c = bcnt[i];
        boffs[i] = excl;
        bcur[i] = excl;
        excl += c;
    }
    if (t == 255) boffs[NBG] = N_EDGES;
}

// pass 1: scatter edges into (group,bucket) segments of the scratch arrays.
__global__ __launch_bounds__(256) void bucket_fill(
    const int* __restrict__ src, const int* __restrict__ dst,
    const float* __restrict__ w, int* __restrict__ bcur,
    int2* __restrict__ sP, int* __restrict__ sD)
{
    int e = blockIdx.x * 256 + threadIdx.x;
    if (e >= N_EDGES) return;
    int d = dst[e];
    int p = atomicAdd(&bcur[(blockIdx.x & 7) * NB2 + (d >> BUCKET_SHIFT)], 1);
    sP[p] = make_int2(src[e], __float_as_int(w[e]));
    sD[p] = d;
}

// pass 2: one block per dst-bucket drains its 8 group segments into node-major ep.
__global__ __launch_bounds__(256) void csr_fill(
    const int* __restrict__ boffs, const int2* __restrict__ sP,
    const int* __restrict__ sD, int* __restrict__ cursor, int2* __restrict__ ep)
{
    int b = blockIdx.x;
    #pragma unroll 1
    for (int g = 0; g < NGRP; g++) {
        int s0 = boffs[g * NB2 + b];
        int s1 = boffs[g * NB2 + b + 1];
        for (int i = s0 + (int)threadIdx.x; i < s1; i += 256) {
            int d = sD[i];
            int p = atomicAdd(&cursor[d], 1);
            ep[p] = sP[i];
        }
    }
}

// ---------------------------------------------------------------------------
// Kernel A: encoder + LN(layer0) + dual GEMM(layer0).  4 lanes x 2 nodes per
// thread. Stage-1 FUSED: hid computed as a scalar per kk and immediately
// broadcast-accumulated (no hid[32] arrays -> ~64 fewer live VGPRs).
// LDS caps at 2 blocks/CU -> declare (256,2) so allocator has 256-VGPR budget
// for weight-prefetch pipelining.
// ---------------------------------------------------------------------------
__global__ __launch_bounds__(256, 2) void enc_ln_gemm(
    const float* __restrict__ x,
    const float* __restrict__ W1, const float* __restrict__ b1,
    const float* __restrict__ W2, const float* __restrict__ b2,
    const float* __restrict__ ln_g, const float* __restrict__ ln_b,
    const float* __restrict__ nodeW, const float* __restrict__ node_b,
    const float* __restrict__ edgeW, const float* __restrict__ edge_b,
    float* __restrict__ H, float* __restrict__ Y, float* __restrict__ Z)
{
    __shared__ float sW1t[128 * 16];   // [k][i] = W1[i][k]
    __shared__ float sW2[128 * 64];
    __shared__ float sNW[64 * 32];
    __shared__ float sEW[64 * 32];
    __shared__ float sb1[128];
    __shared__ float sb2[64];
    __shared__ float sg[64], sb[64], sby[32];
    for (int idx = threadIdx.x; idx < 16 * 128; idx += 256) {
        int i = idx / 128, k = idx % 128;
        sW1t[k * 16 + i] = W1[idx];
    }
    for (int idx = threadIdx.x; idx < 128 * 64; idx += 256) sW2[idx] = W2[idx];
    for (int idx = threadIdx.x; idx < 64 * 32; idx += 256) {
        sNW[idx] = nodeW[idx];
        sEW[idx] = edgeW[idx];
    }
    if (threadIdx.x < 128) sb1[threadIdx.x] = b1[threadIdx.x];
    if (threadIdx.x < 64) {
        sb2[threadIdx.x] = b2[threadIdx.x];
        sg[threadIdx.x] = ln_g[threadIdx.x];
        sb[threadIdx.x] = ln_b[threadIdx.x];
    }
    if (threadIdx.x < 32) sby[threadIdx.x] = node_b[threadIdx.x] + edge_b[threadIdx.x];
    __syncthreads();

    int base = blockIdx.x * 256 + threadIdx.x;
    int pair = base >> 2;
    int q = base & 3;
    if (pair >= NPAIR) return;
    int n0 = pair * 2, n1 = n0 + 1;

    float xi0[16], xi1[16];
    {
        const float4* xv0 = (const float4*)(x + (size_t)n0 * 16);
        const float4* xv1 = (const float4*)(x + (size_t)n1 * 16);
        #pragma unroll
        for (int i = 0; i < 4; i++) {
            float4 t = xv0[i];
            xi0[4 * i] = t.x; xi0[4 * i + 1] = t.y; xi0[4 * i + 2] = t.z; xi0[4 * i + 3] = t.w;
            float4 u = xv1[i];
            xi1[4 * i] = u.x; xi1[4 * i + 1] = u.y; xi1[4 * i + 2] = u.z; xi1[4 * i + 3] = u.w;
        }
    }

    // fused stage 1: per kk, lane q computes hid for t=kk*4+q, then the quad
    // immediately consumes t=kk*4+ss via shfl (same accumulation order as the
    // separate-loop version -> bit-identical).
    float h0[16], h1[16];
    #pragma unroll
    for (int jj = 0; jj < 16; jj++) { h0[jj] = sb2[q * 16 + jj]; h1[jj] = h0[jj]; }
    #pragma unroll 4
    for (int kk = 0; kk < 32; kk++) {
        int t = kk * 4 + q;
        const float4* wv = (const float4*)(sW1t + t * 16);
        float4 w0 = wv[0], w1 = wv[1], w2 = wv[2], w3 = wv[3];
        float a0 = sb1[t];
        a0 += xi0[0] * w0.x + xi0[1] * w0.y + xi0[2] * w0.z + xi0[3] * w0.w;
        a0 += xi0[4] * w1.x + xi0[5] * w1.y + xi0[6] * w1.z + xi0[7] * w1.w;
        a0 += xi0[8] * w2.x + xi0[9] * w2.y + xi0[10] * w2.z + xi0[11] * w2.w;
        a0 += xi0[12] * w3.x + xi0[13] * w3.y + xi0[14] * w3.z + xi0[15] * w3.w;
        float a1 = sb1[t];
        a1 += xi1[0] * w0.x + xi1[1] * w0.y + xi1[2] * w0.z + xi1[3] * w0.w;
        a1 += xi1[4] * w1.x + xi1[5] * w1.y + xi1[6] * w1.z + xi1[7] * w1.w;
        a1 += xi1[8] * w2.x + xi1[9] * w2.y + xi1[10] * w2.z + xi1[11] * w2.w;
        a1 += xi1[12] * w3.x + xi1[13] * w3.y + xi1[14] * w3.z + xi1[15] * w3.w;
        float hv0 = leaky(a0);
        float hv1 = leaky(a1);
        #pragma unroll
        for (int ss = 0; ss < 4; ss++) {
            float v0 = __shfl(hv0, ss, 4);
            float v1 = __shfl(hv1, ss, 4);
            const float4* w = (const float4*)(sW2 + (kk * 4 + ss) * 64 + q * 16);
            float4 a = w[0], b = w[1], c = w[2], d = w[3];
            ACC16(h0, v0, a, b, c, d)
            ACC16(h1, v1, a, b, c, d)
        }
    }

    // LN over quad (both nodes)
    float s0 = 0.f, e0 = 0.f, s1 = 0.f, e1 = 0.f;
    #pragma unroll
    for (int jj = 0; jj < 16; jj++) {
        s0 += h0[jj]; e0 += h0[jj] * h0[jj];
        s1 += h1[jj]; e1 += h1[jj] * h1[jj];
    }
    s0 += __shfl_xor(s0, 1, 4); s0 += __shfl_xor(s0, 2, 4);
    e0 += __shfl_xor(e0, 1, 4); e0 += __shfl_xor(e0, 2, 4);
    s1 += __shfl_xor(s1, 1, 4); s1 += __shfl_xor(s1, 2, 4);
    e1 += __shfl_xor(e1, 1, 4); e1 += __shfl_xor(e1, 2, 4);
    float mu0 = s0 * (1.f / 64.f);
    float va0 = e0 * (1.f / 64.f) - mu0 * mu0;
    float r0  = rsqrtf(va0 + 1e-5f);
    float mu1 = s1 * (1.f / 64.f);
    float va1 = e1 * (1.f / 64.f) - mu1 * mu1;
    float r1  = rsqrtf(va1 + 1e-5f);

    #pragma unroll
    for (int jj = 0; jj < 16; jj++) {
        float g = sg[q * 16 + jj], bb = sb[q * 16 + jj];
        h0[jj] = (h0[jj] - mu0) * r0 * g + bb;   // hn in place
        h1[jj] = (h1[jj] - mu1) * r1 * g + bb;
    }
    {
        float4* hs0 = (float4*)(H + (size_t)n0 * 64 + q * 16);
        float4* hs1 = (float4*)(H + (size_t)n1 * 64 + q * 16);
        #pragma unroll
        for (int c = 0; c < 4; c++) {
            hs0[c] = make_float4(h0[4 * c], h0[4 * c + 1], h0[4 * c + 2], h0[4 * c + 3]);
            hs1[c] = make_float4(h1[4 * c], h1[4 * c + 1], h1[4 * c + 2], h1[4 * c + 3]);
        }
    }

    // dual GEMM: lane owns cols [q*8, q*8+8); k = ss*16 + kk
    float aY0[8], aZ0[8], aY1[8], aZ1[8];
    #pragma unroll
    for (int jj = 0; jj < 8; jj++) {
        aY0[jj] = sby[q * 8 + jj]; aY1[jj] = aY0[jj];
        aZ0[jj] = 0.f; aZ1[jj] = 0.f;
    }
    #pragma unroll
    for (int kk = 0; kk < 16; kk++) {
        #pragma unroll
        for (int ss = 0; ss < 4; ss++) {
            float v0 = __shfl(h0[kk], ss, 4);
            float v1 = __shfl(h1[kk], ss, 4);
            int k = ss * 16 + kk;
            const float4* nw = (const float4*)(sNW + k * 32 + q * 8);
            const float4* ew = (const float4*)(sEW + k * 32 + q * 8);
            float4 a = nw[0], b = nw[1], c = ew[0], d = ew[1];
            ACC8(aY0, v0, a, b)
            ACC8(aZ0, v0, c, d)
            ACC8(aY1, v1, a, b)
            ACC8(aZ1, v1, c, d)
        }
    }
    float4* yv0 = (float4*)(Y + (size_t)n0 * 32 + q * 8);
    float4* zv0 = (float4*)(Z + (size_t)n0 * 32 + q * 8);
    float4* yv1 = (float4*)(Y + (size_t)n1 * 32 + q * 8);
    float4* zv1 = (float4*)(Z + (size_t)n1 * 32 + q * 8);
    yv0[0] = make_float4(aY0[0], aY0[1], aY0[2], aY0[3]);
    yv0[1] = make_float4(aY0[4], aY0[5], aY0[6], aY0[7]);
    zv0[0] = make_float4(aZ0[0], aZ0[1], aZ0[2], aZ0[3]);
    zv0[1] = make_float4(aZ0[4], aZ0[5], aZ0[6], aZ0[7]);
    yv1[0] = make_float4(aY1[0], aY1[1], aY1[2], aY1[3]);
    yv1[1] = make_float4(aY1[4], aY1[5], aY1[6], aY1[7]);
    zv1[0] = make_float4(aZ1[0], aZ1[1], aZ1[2], aZ1[3]);
    zv1[1] = make_float4(aZ1[4], aZ1[5], aZ1[6], aZ1[7]);
}

// ---------------------------------------------------------------------------
// Gather: Y[n] += sum over incoming edges of w_e * Z[src_e]  (8 lanes/node)
// ---------------------------------------------------------------------------
__global__ __launch_bounds__(256) void gather_kernel(
    const int* __restrict__ offs, const int2* __restrict__ ep,
    const float* __restrict__ Z, float* __restrict__ Y)
{
    int gid = blockIdx.x * 256 + threadIdx.x;
    int node = gid >> 3;
    int lane = gid & 7;
    if (node >= N_NODES) return;
    int p0 = offs[node], p1 = offs[node + 1];
    float4 acc = make_float4(0.f, 0.f, 0.f, 0.f);
    const float4* Zv = (const float4*)Z;
    int p = p0;
    for (; p + 2 <= p1; p += 2) {
        int2 ea = ep[p];
        int2 eb = ep[p + 1];
        float wa = __int_as_float(ea.y);
        float wb = __int_as_float(eb.y);
        float4 za = Zv[(size_t)ea.x * 8 + lane];
        float4 zb = Zv[(size_t)eb.x * 8 + lane];
        acc.x += wa * za.x + wb * zb.x;
        acc.y += wa * za.y + wb * zb.y;
        acc.z += wa * za.z + wb * zb.z;
        acc.w += wa * za.w + wb * zb.w;
    }
    if (p < p1) {
        int2 ea = ep[p];
        float wa = __int_as_float(ea.y);
        float4 za = Zv[(size_t)ea.x * 8 + lane];
        acc.x += wa * za.x; acc.y += wa * za.y;
        acc.z += wa * za.z; acc.w += wa * za.w;
    }
    float4* yp = (float4*)(Y + (size_t)node * 32) + lane;
    float4 y = *yp;
    y.x += acc.x; y.y += acc.y; y.z += acc.z; y.w += acc.w;
    *yp = y;
}

// ---------------------------------------------------------------------------
// Kernel B: mlp+residual (layer l) then LN + dual GEMM (layer l+1).
// 4 lanes x 2 nodes per thread; (256,3) -> VGPR cap ~170, 12 waves/CU.
// ---------------------------------------------------------------------------
__global__ __launch_bounds__(256, 3) void mlp_ln_gemm(
    float* __restrict__ Yio, float* __restrict__ H, float* __restrict__ Z,
    const float* __restrict__ mlpW, const float* __restrict__ mlp_b,
    const float* __restrict__ ln_g, const float* __restrict__ ln_b,
    const float* __restrict__ nodeW, const float* __restrict__ node_b,
    const float* __restrict__ edgeW, const float* __restrict__ edge_b)
{
    __shared__ float sMW[32 * 64];
    __shared__ float sNW[64 * 32];
    __shared__ float sEW[64 * 32];
    __shared__ float smb[64], sg[64], sb[64], sby[32];
    for (int idx = threadIdx.x; idx < 32 * 64; idx += 256) sMW[idx] = mlpW[idx];
    for (int idx = threadIdx.x; idx < 64 * 32; idx += 256) {
        sNW[idx] = nodeW[idx];
        sEW[idx] = edgeW[idx];
    }
    if (threadIdx.x < 64) {
        smb[threadIdx.x] = mlp_b[threadIdx.x];
        sg[threadIdx.x] = ln_g[threadIdx.x];
        sb[threadIdx.x] = ln_b[threadIdx.x];
    }
    if (threadIdx.x < 32) sby[threadIdx.x] = node_b[threadIdx.x] + edge_b[threadIdx.x];
    __syncthreads();

    int base = blockIdx.x * 256 + threadIdx.x;
    int pair = base >> 2;
    int q = base & 3;
    if (pair >= NPAIR) return;
    int n0 = pair * 2, n1 = n0 + 1;

    float ly0[8], ly1[8];
    {
        const float4* yv0 = (const float4*)(Yio + (size_t)n0 * 32 + q * 8);
        const float4* yv1 = (const float4*)(Yio + (size_t)n1 * 32 + q * 8);
        float4 t0 = yv0[0], t1 = yv0[1];
        ly0[0] = leaky(t0.x); ly0[1] = leaky(t0.y); ly0[2] = leaky(t0.z); ly0[3] = leaky(t0.w);
        ly0[4] = leaky(t1.x); ly0[5] = leaky(t1.y); ly0[6] = leaky(t1.z); ly0[7] = leaky(t1.w);
        float4 u0 = yv1[0], u1 = yv1[1];
        ly1[0] = leaky(u0.x); ly1[1] = leaky(u0.y); ly1[2] = leaky(u0.z); ly1[3] = leaky(u0.w);
        ly1[4] = leaky(u1.x); ly1[5] = leaky(u1.y); ly1[6] = leaky(u1.z); ly1[7] = leaky(u1.w);
    }

    float h0[16], h1[16];
    #pragma unroll
    for (int jj = 0; jj < 16; jj++) { h0[jj] = smb[q * 16 + jj]; h1[jj] = h0[jj]; }
    #pragma unroll
    for (int kk = 0; kk < 8; kk++) {
        #pragma unroll
        for (int ss = 0; ss < 4; ss++) {
            float v0 = __shfl(ly0[kk], ss, 4);
            float v1 = __shfl(ly1[kk], ss, 4);
            const float4* w = (const float4*)(sMW + (ss * 8 + kk) * 64 + q * 16);
            float4 a = w[0], b = w[1], c = w[2], d = w[3];
            ACC16(h0, v0, a, b, c, d)
            ACC16(h1, v1, a, b, c, d)
        }
    }
    // residual
    float4* hp0 = (float4*)(H + (size_t)n0 * 64 + q * 16);
    float4* hp1 = (float4*)(H + (size_t)n1 * 64 + q * 16);
    #pragma unroll
    for (int c = 0; c < 4; c++) {
        float4 r0 = hp0[c];
        h0[4 * c] += r0.x; h0[4 * c + 1] += r0.y; h0[4 * c + 2] += r0.z; h0[4 * c + 3] += r0.w;
        float4 r1 = hp1[c];
        h1[4 * c] += r1.x; h1[4 * c + 1] += r1.y; h1[4 * c + 2] += r1.z; h1[4 * c + 3] += r1.w;
    }
    // LN over quad
    float s0 = 0.f, e0 = 0.f, s1 = 0.f, e1 = 0.f;
    #pragma unroll
    for (int jj = 0; jj < 16; jj++) {
        s0 += h0[jj]; e0 += h0[jj] * h0[jj];
        s1 += h1[jj]; e1 += h1[jj] * h1[jj];
    }
    s0 += __shfl_xor(s0, 1, 4); s0 += __shfl_xor(s0, 2, 4);
    e0 += __shfl_xor(e0, 1, 4); e0 += __shfl_xor(e0, 2, 4);
    s1 += __shfl_xor(s1, 1, 4); s1 += __shfl_xor(s1, 2, 4);
    e1 += __shfl_xor(e1, 1, 4); e1 += __shfl_xor(e1, 2, 4);
    float mu0 = s0 * (1.f / 64.f);
    float va0 = e0 * (1.f / 64.f) - mu0 * mu0;
    float r0  = rsqrtf(va0 + 1e-5f);
    float mu1 = s1 * (1.f / 64.f);
    float va1 = e1 * (1.f / 64.f) - mu1 * mu1;
    float r1  = rsqrtf(va1 + 1e-5f);

    #pragma unroll
    for (int jj = 0; jj < 16; jj++) {
        float g = sg[q * 16 + jj], bb = sb[q * 16 + jj];
        h0[jj] = (h0[jj] - mu0) * r0 * g + bb;
        h1[jj] = (h1[jj] - mu1) * r1 * g + bb;
    }
    #pragma unroll
    for (int c = 0; c < 4; c++) {
        hp0[c] = make_float4(h0[4 * c], h0[4 * c + 1], h0[4 * c + 2], h0[4 * c + 3]);
        hp1[c] = make_float4(h1[4 * c], h1[4 * c + 1], h1[4 * c + 2], h1[4 * c + 3]);
    }

    // dual GEMM
    float aY0[8], aZ0[8], aY1[8], aZ1[8];
    #pragma unroll
    for (int jj = 0; jj < 8; jj++) {
        aY0[jj] = sby[q * 8 + jj]; aY1[jj] = aY0[jj];
        aZ0[jj] = 0.f; aZ1[jj] = 0.f;
    }
    #pragma unroll
    for (int kk = 0; kk < 16; kk++) {
        #pragma unroll
        for (int ss = 0; ss < 4; ss++) {
            float v0 = __shfl(h0[kk], ss, 4);
            float v1 = __shfl(h1[kk], ss, 4);
            int k = ss * 16 + kk;
            const float4* nw = (const float4*)(sNW + k * 32 + q * 8);
            const float4* ew = (const float4*)(sEW + k * 32 + q * 8);
            float4 a = nw[0], b = nw[1], c = ew[0], d = ew[1];
            ACC8(aY0, v0, a, b)
            ACC8(aZ0, v0, c, d)
            ACC8(aY1, v1, a, b)
            ACC8(aZ1, v1, c, d)
        }
    }
    float4* yo0 = (float4*)(Yio + (size_t)n0 * 32 + q * 8);
    float4* zo0 = (float4*)(Z + (size_t)n0 * 32 + q * 8);
    float4* yo1 = (float4*)(Yio + (size_t)n1 * 32 + q * 8);
    float4* zo1 = (float4*)(Z + (size_t)n1 * 32 + q * 8);
    yo0[0] = make_float4(aY0[0], aY0[1], aY0[2], aY0[3]);
    yo0[1] = make_float4(aY0[4], aY0[5], aY0[6], aY0[7]);
    zo0[0] = make_float4(aZ0[0], aZ0[1], aZ0[2], aZ0[3]);
    zo0[1] = make_float4(aZ0[4], aZ0[5], aZ0[6], aZ0[7]);
    yo1[0] = make_float4(aY1[0], aY1[1], aY1[2], aY1[3]);
    yo1[1] = make_float4(aY1[4], aY1[5], aY1[6], aY1[7]);
    zo1[0] = make_float4(aZ1[0], aZ1[1], aZ1[2], aZ1[3]);
    zo1[1] = make_float4(aZ1[4], aZ1[5], aZ1[6], aZ1[7]);
}

// ---------------------------------------------------------------------------
// Kernel C: mlp+residual (layer 3) then decoder.  4 lanes x 2 nodes/thread.
// ---------------------------------------------------------------------------
__global__ __launch_bounds__(256, 3) void mlp_dec(
    const float* __restrict__ Y, const float* __restrict__ H,
    const float* __restrict__ mlpW, const float* __restrict__ mlp_b,
    const float* __restrict__ dW1, const float* __restrict__ db1,
    const float* __restrict__ dW2, const float* __restrict__ db2,
    float* __restrict__ out)
{
    __shared__ float sMW[32 * 64];
    __shared__ float smb[64];
    __shared__ float sW1t[24 * 65];   // [t][k] = dW1[k][t], stride 65 (bank spread)
    __shared__ float sb1[24];
    __shared__ float sW2[24 * 3];
    __shared__ float sb2v[3];
    for (int idx = threadIdx.x; idx < 32 * 64; idx += 256) sMW[idx] = mlpW[idx];
    for (int idx = threadIdx.x; idx < 64 * 24; idx += 256) {
        int k = idx / 24, t = idx % 24;
        sW1t[t * 65 + k] = dW1[idx];
    }
    if (threadIdx.x < 64) smb[threadIdx.x] = mlp_b[threadIdx.x];
    if (threadIdx.x < 24) sb1[threadIdx.x] = db1[threadIdx.x];
    if (threadIdx.x < 72) sW2[threadIdx.x] = dW2[threadIdx.x];
    if (threadIdx.x < 3)  sb2v[threadIdx.x] = db2[threadIdx.x];
    __syncthreads();

    int base = blockIdx.x * 256 + threadIdx.x;
    int pair = base >> 2;
    int q = base & 3;
    if (pair >= NPAIR) return;
    int n0 = pair * 2, n1 = n0 + 1;

    float ly0[8], ly1[8];
    {
        const float4* yv0 = (const float4*)(Y + (size_t)n0 * 32 + q * 8);
        const float4* yv1 = (const float4*)(Y + (size_t)n1 * 32 + q * 8);
        float4 t0 = yv0[0], t1 = yv0[1];
        ly0[0] = leaky(t0.x); ly0[1] = leaky(t0.y); ly0[2] = leaky(t0.z); ly0[3] = leaky(t0.w);
        ly0[4] = leaky(t1.x); ly0[5] = leaky(t1.y); ly0[6] = leaky(t1.z); ly0[7] = leaky(t1.w);
        float4 u0 = yv1[0], u1 = yv1[1];
        ly1[0] = leaky(u0.x); ly1[1] = leaky(u0.y); ly1[2] = leaky(u0.z); ly1[3] = leaky(u0.w);
        ly1[4] = leaky(u1.x); ly1[5] = leaky(u1.y); ly1[6] = leaky(u1.z); ly1[7] = leaky(u1.w);
    }
    float h0[16], h1[16];
    #pragma unroll
    for (int jj = 0; jj < 16; jj++) { h0[jj] = smb[q * 16 + jj]; h1[jj] = h0[jj]; }
    #pragma unroll
    for (int kk = 0; kk < 8; kk++) {
        #pragma unroll
        for (int ss = 0; ss < 4; ss++) {
            float v0 = __shfl(ly0[kk], ss, 4);
            float v1 = __shfl(ly1[kk], ss, 4);
            const float4* w = (const float4*)(sMW + (ss * 8 + kk) * 64 + q * 16);
            float4 a = w[0], b = w[1], c = w[2], d = w[3];
            ACC16(h0, v0, a, b, c, d)
            ACC16(h1, v1, a, b, c, d)
        }
    }
    {
        const float4* hp0 = (const float4*)(H + (size_t)n0 * 64 + q * 16);
        const float4* hp1 = (const float4*)(H + (size_t)n1 * 64 + q * 16);
        #pragma unroll
        for (int c = 0; c < 4; c++) {
            float4 r0 = hp0[c];
            h0[4 * c] += r0.x; h0[4 * c + 1] += r0.y; h0[4 * c + 2] += r0.z; h0[4 * c + 3] += r0.w;
            float4 r1 = hp1[c];
            h1[4 * c] += r1.x; h1[4 * c + 1] += r1.y; h1[4 * c + 2] += r1.z; h1[4 * c + 3] += r1.w;
        }
    }
    // decoder hidden: lane q owns t in [q*6, q*6+6); k = ss*16+kk via shfl
    float hd0[6], hd1[6];
    #pragma unroll
    for (int t = 0; t < 6; t++) { hd0[t] = sb1[q * 6 + t]; hd1[t] = hd0[t]; }
    #pragma unroll
    for (int kk = 0; kk < 16; kk++) {
        #pragma unroll
        for (int ss = 0; ss < 4; ss++) {
            float v0 = __shfl(h0[kk], ss, 4);
            float v1 = __shfl(h1[kk], ss, 4);
            int k = ss * 16 + kk;
            #pragma unroll
            for (int t = 0; t < 6; t++) {
                float wv = sW1t[(q * 6 + t) * 65 + k];
                hd0[t] += v0 * wv;
                hd1[t] += v1 * wv;
            }
        }
    }
    float o00 = 0.f, o01 = 0.f, o02 = 0.f;
    float o10 = 0.f, o11 = 0.f, o12 = 0.f;
    #pragma unroll
    for (int t = 0; t < 6; t++) {
        int tg = q * 6 + t;
        float w0 = sW2[tg * 3 + 0], w1 = sW2[tg * 3 + 1], w2 = sW2[tg * 3 + 2];
        float l0 = leaky(hd0[t]);
        o00 += l0 * w0; o01 += l0 * w1; o02 += l0 * w2;
        float l1 = leaky(hd1[t]);
        o10 += l1 * w0; o11 += l1 * w1; o12 += l1 * w2;
    }
    o00 += __shfl_xor(o00, 1, 4); o00 += __shfl_xor(o00, 2, 4);
    o01 += __shfl_xor(o01, 1, 4); o01 += __shfl_xor(o01, 2, 4);
    o02 += __shfl_xor(o02, 1, 4); o02 += __shfl_xor(o02, 2, 4);
    o10 += __shfl_xor(o10, 1, 4); o10 += __shfl_xor(o10, 2, 4);
    o11 += __shfl_xor(o11, 1, 4); o11 += __shfl_xor(o11, 2, 4);
    o12 += __shfl_xor(o12, 1, 4); o12 += __shfl_xor(o12, 2, 4);
    if (q == 0) {
        float* op0 = out + (size_t)n0 * 3;
        op0[0] = o00 + sb2v[0]; op0[1] = o01 + sb2v[1]; op0[2] = o02 + sb2v[2];
        float* op1 = out + (size_t)n1 * 3;
        op1[0] = o10 + sb2v[0]; op1[1] = o11 + sb2v[1]; op1[2] = o12 + sb2v[2];
    }
}

// ---------------------------------------------------------------------------
extern "C" void kernel_launch(void* const* d_in, const int* in_sizes, int n_in,
                              void* d_out, int out_size, void* d_ws, size_t ws_size,
                              hipStream_t stream)
{
    const float* x      = (const float*)d_in[0];
    const int*   esrc   = (const int*)d_in[2];
    const int*   edst   = (const int*)d_in[3];
    const float* ew     = (const float*)d_in[4];
    const float* enc_W1 = (const float*)d_in[5];
    const float* enc_b1 = (const float*)d_in[6];
    const float* enc_W2 = (const float*)d_in[7];
    const float* enc_b2 = (const float*)d_in[8];
    const float* dec_W1 = (const float*)d_in[9];
    const float* dec_b1 = (const float*)d_in[10];
    const float* dec_W2 = (const float*)d_in[11];
    const float* dec_b2 = (const float*)d_in[12];
    const float* ln_g   = (const float*)d_in[13];
    const float* ln_b   = (const float*)d_in[14];
    const float* node_W = (const float*)d_in[15];
    const float* node_b = (const float*)d_in[16];
    const float* edge_W = (const float*)d_in[17];
    const float* edge_b = (const float*)d_in[18];
    const float* mlp_W  = (const float*)d_in[19];
    const float* mlp_b  = (const float*)d_in[20];

    // Workspace: floats H[N*64] | Y[N*32] | Z[N*32] | ep[E int2]
    //            ints counts[N] | offs[N+1] | cursor[N] | bsum | bscan
    float* H  = (float*)d_ws;
    float* Y  = H + (size_t)N_NODES * 64;
    float* Z  = Y + (size_t)N_NODES * 32;
    int2*  ep = (int2*)(Z + (size_t)N_NODES * 32);
    int* counts = (int*)(ep + N_EDGES);
    int* offs   = counts + N_NODES;          // N_NODES+1 entries
    int* cursor = offs + N_NODES + 1;
    int* bsum   = cursor + N_NODES;
    int* bscan  = bsum + NB1;
    // CSR-build scratch aliased over H (H is dead until enc_ln_gemm runs):
    int2* sP   = (int2*)H;
    int*  sD   = (int*)(sP + N_EDGES);
    int*  bcnt  = sD + N_EDGES;
    int*  boffs = bcnt + NBG;
    int*  bcur  = boffs + NBG + 1;

    const int nodeBlocks   = (N_NODES + 255) / 256;
    const int pairBlocks   = (NPAIR * 4 + 255) / 256;
    const int edgeBlocks   = (N_EDGES + 255) / 256;
    const int gatherBlocks = (N_NODES * 8 + 255) / 256;

    // --- CSR build (bucketed counting sort by dst) ---
    zero_counts<<<nodeBlocks, 256, 0, stream>>>(counts, bcnt);
    hist_kernel<<<edgeBlocks, 256, 0, stream>>>(edst, counts, bcnt);
    scan1_kernel<<<NB1, 256, 0, stream>>>(counts, offs, bsum);
    scan2_kernel<<<1, 128, 0, stream>>>(bsum, bscan);
    scan3_kernel<<<NB1, 256, 0, stream>>>(offs, cursor, bscan);
    bucket_scan<<<1, 256, 0, stream>>>(bcnt, boffs, bcur);
    bucket_fill<<<edgeBlocks, 256, 0, stream>>>(esrc, edst, ew, bcur, sP, sD);
    csr_fill<<<NB2, 256, 0, stream>>>(boffs, sP, sD, cursor, ep);

    // --- network ---
    enc_ln_gemm<<<pairBlocks, 256, 0, stream>>>(
        x, enc_W1, enc_b1, enc_W2, enc_b2,
        ln_g, ln_b, node_W, node_b, edge_W, edge_b, H, Y, Z);

    for (int l = 0; l < LAYERS - 1; l++) {
        gather_kernel<<<gatherBlocks, 256, 0, stream>>>(offs, ep, Z, Y);
        mlp_ln_gemm<<<pairBlocks, 256, 0, stream>>>(
            Y, H, Z,
            mlp_W + l * 32 * 64, mlp_b + l * 64,
            ln_g + (l + 1) * 64, ln_b + (l + 1) * 64,
            node_W + (l + 1) * 64 * 32, node_b + (l + 1) * 32,
            edge_W + (l + 1) * 64 * 32, edge_b + (l + 1) * 32);
    }
    gather_kernel<<<gatherBlocks, 256, 0, stream>>>(offs, ep, Z, Y);
    mlp_dec<<<pairBlocks, 256, 0, stream>>>(
        Y, H, mlp_W + 3 * 32 * 64, mlp_b + 3 * 64,
        dec_W1, dec_b1, dec_W2, dec_b2, (float*)d_out);
}

// Round 3
// 646.473 us; speedup vs baseline: 1.4257x; 1.4257x over previous
//
#include <hip/hip_runtime.h>

#define N_NODES 100000
#define N_EDGES 1200000
#define LAYERS 4
#define SLOPE 0.01f

#define SCAN_ELEMS 1024                     // elems per scan1 block (256 thr x 4)
#define NB1 ((N_NODES + SCAN_ELEMS - 1) / SCAN_ELEMS)   // 98

// edge bucketing: 8 block-groups (XCD heuristic) x 782 dst-buckets (128 nodes each)
#define BUCKET_SHIFT 7
#define NB2 ((N_NODES + 127) >> 7)          // 782
#define NGRP 8
#define NBG (NB2 * NGRP)                    // 6256

__device__ __forceinline__ float leaky(float v) { return v >= 0.f ? v : SLOPE * v; }

#define ACC16(h, v, a, b, c, d) \
    h[0]  += v * a.x; h[1]  += v * a.y; h[2]  += v * a.z; h[3]  += v * a.w; \
    h[4]  += v * b.x; h[5]  += v * b.y; h[6]  += v * b.z; h[7]  += v * b.w; \
    h[8]  += v * c.x; h[9]  += v * c.y; h[10] += v * c.z; h[11] += v * c.w; \
    h[12] += v * d.x; h[13] += v * d.y; h[14] += v * d.z; h[15] += v * d.w;

#define ACC8(r, v, a, b) \
    r[0] += v * a.x; r[1] += v * a.y; r[2] += v * a.z; r[3] += v * a.w; \
    r[4] += v * b.x; r[5] += v * b.y; r[6] += v * b.z; r[7] += v * b.w;

// ---------------------------------------------------------------------------
// CSR build (counting sort by edge_dst, bucketed to kill write amplification)
// ---------------------------------------------------------------------------
__global__ __launch_bounds__(256) void zero_counts(
    int* __restrict__ counts, int* __restrict__ bcnt)
{
    int i = blockIdx.x * 256 + threadIdx.x;
    if (i < N_NODES) counts[i] = 0;
    if (i < NBG) bcnt[i] = 0;
}

__global__ __launch_bounds__(256) void hist_kernel(
    const int* __restrict__ dst, int* __restrict__ counts, int* __restrict__ bcnt)
{
    int e = blockIdx.x * 256 + threadIdx.x;
    if (e >= N_EDGES) return;
    int d = dst[e];
    atomicAdd(&counts[d], 1);
    atomicAdd(&bcnt[(blockIdx.x & 7) * NB2 + (d >> BUCKET_SHIFT)], 1);
}

__global__ __launch_bounds__(256) void scan1_kernel(
    const int* __restrict__ counts, int* __restrict__ offs, int* __restrict__ bsum)
{
    __shared__ int s[256];
    int b = blockIdx.x, t = threadIdx.x;
    int base = b * SCAN_ELEMS;
    int v[4]; int sum = 0;
    #pragma unroll
    for (int u = 0; u < 4; u++) {
        int idx = base + t * 4 + u;
        int c = (idx < N_NODES) ? counts[idx] : 0;
        v[u] = sum; sum += c;
    }
    s[t] = sum; __syncthreads();
    for (int off = 1; off < 256; off <<= 1) {
        int y = (t >= off) ? s[t - off] : 0;
        __syncthreads();
        s[t] += y;
        __syncthreads();
    }
    int excl = s[t] - sum;
    #pragma unroll
    for (int u = 0; u < 4; u++) {
        int idx = base + t * 4 + u;
        if (idx < N_NODES) offs[idx] = excl + v[u];
    }
    if (t == 255) bsum[b] = s[255];
}

__global__ __launch_bounds__(128) void scan2_kernel(
    const int* __restrict__ bsum, int* __restrict__ bscan)
{
    __shared__ int s[128];
    int t = threadIdx.x;
    int c = (t < NB1) ? bsum[t] : 0;
    s[t] = c; __syncthreads();
    for (int off = 1; off < 128; off <<= 1) {
        int y = (t >= off) ? s[t - off] : 0;
        __syncthreads();
        s[t] += y;
        __syncthreads();
    }
    if (t < NB1) bscan[t] = s[t] - c;
}

__global__ __launch_bounds__(256) void scan3_kernel(
    int* __restrict__ offs, int* __restrict__ cursor, const int* __restrict__ bscan)
{
    int b = blockIdx.x, t = threadIdx.x;
    int base = b * SCAN_ELEMS;
    int add = bscan[b];
    #pragma unroll
    for (int u = 0; u < 4; u++) {
        int idx = base + t * 4 + u;
        if (idx < N_NODES) {
            int v = offs[idx] + add;
            offs[idx] = v;
            cursor[idx] = v;
        }
    }
    if (b == 0 && t == 0) offs[N_NODES] = N_EDGES;
}

// exclusive scan of the 6256 (group,bucket) counts; writes offsets + cursor copy
__global__ __launch_bounds__(256) void bucket_scan(
    const int* __restrict__ bcnt, int* __restrict__ boffs, int* __restrict__ bcur)
{
    __shared__ int s[256];
    int t = threadIdx.x;
    int beg = t * 25;
    int end = beg + 25; if (end > NBG) end = NBG;
    int sum = 0;
    for (int i = beg; i < end; i++) sum += bcnt[i];
    s[t] = sum; __syncthreads();
    for (int off = 1; off < 256; off <<= 1) {
        int y = (t >= off) ? s[t - off] : 0;
        __syncthreads();
        s[t] += y;
        __syncthreads();
    }
    int excl = s[t] - sum;
    for (int i = beg; i < end; i++) {
        int c = bcnt[i];
        boffs[i] = excl;
        bcur[i] = excl;
        excl += c;
    }
    if (t == 255) boffs[NBG] = N_EDGES;
}

// pass 1: scatter edges into (group,bucket) segments of the scratch arrays.
__global__ __launch_bounds__(256) void bucket_fill(
    const int* __restrict__ src, const int* __restrict__ dst,
    const float* __restrict__ w, int* __restrict__ bcur,
    int2* __restrict__ sP, int* __restrict__ sD)
{
    int e = blockIdx.x * 256 + threadIdx.x;
    if (e >= N_EDGES) return;
    int d = dst[e];
    int p = atomicAdd(&bcur[(blockIdx.x & 7) * NB2 + (d >> BUCKET_SHIFT)], 1);
    sP[p] = make_int2(src[e], __float_as_int(w[e]));
    sD[p] = d;
}

// pass 2: one block per dst-bucket drains its 8 group segments into node-major ep.
__global__ __launch_bounds__(256) void csr_fill(
    const int* __restrict__ boffs, const int2* __restrict__ sP,
    const int* __restrict__ sD, int* __restrict__ cursor, int2* __restrict__ ep)
{
    int b = blockIdx.x;
    #pragma unroll 1
    for (int g = 0; g < NGRP; g++) {
        int s0 = boffs[g * NB2 + b];
        int s1 = boffs[g * NB2 + b + 1];
        for (int i = s0 + (int)threadIdx.x; i < s1; i += 256) {
            int d = sD[i];
            int p = atomicAdd(&cursor[d], 1);
            ep[p] = sP[i];
        }
    }
}

// ---------------------------------------------------------------------------
// Kernel A: encoder + LN(layer0) + dual GEMM(layer0).  4 lanes per node
// (round-0 structure). Single change: stage-1 fused into stage-2 (no hid[32]
// array -> ~32 fewer live VGPRs; identical FP accumulation order).
// ---------------------------------------------------------------------------
__global__ __launch_bounds__(256) void enc_ln_gemm(
    const float* __restrict__ x,
    const float* __restrict__ W1, const float* __restrict__ b1,
    const float* __restrict__ W2, const float* __restrict__ b2,
    const float* __restrict__ ln_g, const float* __restrict__ ln_b,
    const float* __restrict__ nodeW, const float* __restrict__ node_b,
    const float* __restrict__ edgeW, const float* __restrict__ edge_b,
    float* __restrict__ H, float* __restrict__ Y, float* __restrict__ Z)
{
    __shared__ float sW1t[128 * 16];   // [k][i] = W1[i][k]
    __shared__ float sW2[128 * 64];
    __shared__ float sNW[64 * 32];
    __shared__ float sEW[64 * 32];
    __shared__ float sb1[128];
    __shared__ float sb2[64];
    __shared__ float sg[64], sb[64], sby[32];
    for (int idx = threadIdx.x; idx < 16 * 128; idx += 256) {
        int i = idx / 128, k = idx % 128;
        sW1t[k * 16 + i] = W1[idx];
    }
    for (int idx = threadIdx.x; idx < 128 * 64; idx += 256) sW2[idx] = W2[idx];
    for (int idx = threadIdx.x; idx < 64 * 32; idx += 256) {
        sNW[idx] = nodeW[idx];
        sEW[idx] = edgeW[idx];
    }
    if (threadIdx.x < 128) sb1[threadIdx.x] = b1[threadIdx.x];
    if (threadIdx.x < 64) {
        sb2[threadIdx.x] = b2[threadIdx.x];
        sg[threadIdx.x] = ln_g[threadIdx.x];
        sb[threadIdx.x] = ln_b[threadIdx.x];
    }
    if (threadIdx.x < 32) sby[threadIdx.x] = node_b[threadIdx.x] + edge_b[threadIdx.x];
    __syncthreads();

    int gid = blockIdx.x * 256 + threadIdx.x;
    int node = gid >> 2;
    int q = gid & 3;
    if (node >= N_NODES) return;

    float xi[16];
    const float4* xv = (const float4*)(x + (size_t)node * 16);
    #pragma unroll
    for (int i = 0; i < 4; i++) {
        float4 t = xv[i];
        xi[4 * i] = t.x; xi[4 * i + 1] = t.y; xi[4 * i + 2] = t.z; xi[4 * i + 3] = t.w;
    }

    // fused: per kk, lane q computes hid for t=kk*4+q, quad immediately
    // consumes t=kk*4+ss via shfl (same order as split loops -> bit-identical)
    float h[16];
    #pragma unroll
    for (int jj = 0; jj < 16; jj++) h[jj] = sb2[q * 16 + jj];
    #pragma unroll 4
    for (int kk = 0; kk < 32; kk++) {
        int t = kk * 4 + q;
        const float4* wv = (const float4*)(sW1t + t * 16);
        float4 w0 = wv[0], w1 = wv[1], w2 = wv[2], w3 = wv[3];
        float a = sb1[t];
        a += xi[0] * w0.x + xi[1] * w0.y + xi[2] * w0.z + xi[3] * w0.w;
        a += xi[4] * w1.x + xi[5] * w1.y + xi[6] * w1.z + xi[7] * w1.w;
        a += xi[8] * w2.x + xi[9] * w2.y + xi[10] * w2.z + xi[11] * w2.w;
        a += xi[12] * w3.x + xi[13] * w3.y + xi[14] * w3.z + xi[15] * w3.w;
        float hv = leaky(a);
        #pragma unroll
        for (int ss = 0; ss < 4; ss++) {
            float v = __shfl(hv, ss, 4);
            const float4* w = (const float4*)(sW2 + (kk * 4 + ss) * 64 + q * 16);
            float4 aa = w[0], bb = w[1], cc = w[2], dd = w[3];
            ACC16(h, v, aa, bb, cc, dd)
        }
    }

    // LN over quad
    float s = 0.f, s2 = 0.f;
    #pragma unroll
    for (int jj = 0; jj < 16; jj++) { s += h[jj]; s2 += h[jj] * h[jj]; }
    s  += __shfl_xor(s, 1, 4);  s  += __shfl_xor(s, 2, 4);
    s2 += __shfl_xor(s2, 1, 4); s2 += __shfl_xor(s2, 2, 4);
    float mu  = s * (1.f / 64.f);
    float var = s2 * (1.f / 64.f) - mu * mu;
    float rs  = rsqrtf(var + 1e-5f);

    float hn[16];
    #pragma unroll
    for (int jj = 0; jj < 16; jj++)
        hn[jj] = (h[jj] - mu) * rs * sg[q * 16 + jj] + sb[q * 16 + jj];

    float4* hs = (float4*)(H + (size_t)node * 64 + q * 16);
    #pragma unroll
    for (int c = 0; c < 4; c++)
        hs[c] = make_float4(hn[4 * c], hn[4 * c + 1], hn[4 * c + 2], hn[4 * c + 3]);

    // dual GEMM: lane owns cols [q*8, q*8+8); k = ss*16 + kk
    float aY[8], aZ[8];
    #pragma unroll
    for (int jj = 0; jj < 8; jj++) { aY[jj] = sby[q * 8 + jj]; aZ[jj] = 0.f; }
    #pragma unroll
    for (int kk = 0; kk < 16; kk++) {
        #pragma unroll
        for (int ss = 0; ss < 4; ss++) {
            float v = __shfl(hn[kk], ss, 4);
            int k = ss * 16 + kk;
            const float4* nw = (const float4*)(sNW + k * 32 + q * 8);
            const float4* ew = (const float4*)(sEW + k * 32 + q * 8);
            float4 a = nw[0], b = nw[1], c = ew[0], d = ew[1];
            ACC8(aY, v, a, b)
            ACC8(aZ, v, c, d)
        }
    }
    float4* yv = (float4*)(Y + (size_t)node * 32 + q * 8);
    float4* zv = (float4*)(Z + (size_t)node * 32 + q * 8);
    yv[0] = make_float4(aY[0], aY[1], aY[2], aY[3]);
    yv[1] = make_float4(aY[4], aY[5], aY[6], aY[7]);
    zv[0] = make_float4(aZ[0], aZ[1], aZ[2], aZ[3]);
    zv[1] = make_float4(aZ[4], aZ[5], aZ[6], aZ[7]);
}

// ---------------------------------------------------------------------------
// Gather: Y[n] += sum over incoming edges of w_e * Z[src_e]  (8 lanes/node)
// unroll-by-2: keep 2 random Z loads in flight per lane
// ---------------------------------------------------------------------------
__global__ __launch_bounds__(256) void gather_kernel(
    const int* __restrict__ offs, const int2* __restrict__ ep,
    const float* __restrict__ Z, float* __restrict__ Y)
{
    int gid = blockIdx.x * 256 + threadIdx.x;
    int node = gid >> 3;
    int lane = gid & 7;
    if (node >= N_NODES) return;
    int p0 = offs[node], p1 = offs[node + 1];
    float4 acc = make_float4(0.f, 0.f, 0.f, 0.f);
    const float4* Zv = (const float4*)Z;
    int p = p0;
    for (; p + 2 <= p1; p += 2) {
        int2 ea = ep[p];
        int2 eb = ep[p + 1];
        float wa = __int_as_float(ea.y);
        float wb = __int_as_float(eb.y);
        float4 za = Zv[(size_t)ea.x * 8 + lane];
        float4 zb = Zv[(size_t)eb.x * 8 + lane];
        acc.x += wa * za.x + wb * zb.x;
        acc.y += wa * za.y + wb * zb.y;
        acc.z += wa * za.z + wb * zb.z;
        acc.w += wa * za.w + wb * zb.w;
    }
    if (p < p1) {
        int2 ea = ep[p];
        float wa = __int_as_float(ea.y);
        float4 za = Zv[(size_t)ea.x * 8 + lane];
        acc.x += wa * za.x; acc.y += wa * za.y;
        acc.z += wa * za.z; acc.w += wa * za.w;
    }
    float4* yp = (float4*)(Y + (size_t)node * 32) + lane;
    float4 y = *yp;
    y.x += acc.x; y.y += acc.y; y.z += acc.z; y.w += acc.w;
    *yp = y;
}

// ---------------------------------------------------------------------------
// Kernel B: mlp+residual (layer l) then LN + dual GEMM (layer l+1).
// Round-0 verbatim: 4 lanes per node, 1 node per thread, plain bounds.
// ---------------------------------------------------------------------------
__global__ __launch_bounds__(256) void mlp_ln_gemm(
    float* __restrict__ Yio, float* __restrict__ H, float* __restrict__ Z,
    const float* __restrict__ mlpW, const float* __restrict__ mlp_b,
    const float* __restrict__ ln_g, const float* __restrict__ ln_b,
    const float* __restrict__ nodeW, const float* __restrict__ node_b,
    const float* __restrict__ edgeW, const float* __restrict__ edge_b)
{
    __shared__ float sMW[32 * 64];
    __shared__ float sNW[64 * 32];
    __shared__ float sEW[64 * 32];
    __shared__ float smb[64], sg[64], sb[64], sby[32];
    for (int idx = threadIdx.x; idx < 32 * 64; idx += 256) sMW[idx] = mlpW[idx];
    for (int idx = threadIdx.x; idx < 64 * 32; idx += 256) {
        sNW[idx] = nodeW[idx];
        sEW[idx] = edgeW[idx];
    }
    if (threadIdx.x < 64) {
        smb[threadIdx.x] = mlp_b[threadIdx.x];
        sg[threadIdx.x] = ln_g[threadIdx.x];
        sb[threadIdx.x] = ln_b[threadIdx.x];
    }
    if (threadIdx.x < 32) sby[threadIdx.x] = node_b[threadIdx.x] + edge_b[threadIdx.x];
    __syncthreads();

    int gid = blockIdx.x * 256 + threadIdx.x;
    int node = gid >> 2;
    int q = gid & 3;
    if (node >= N_NODES) return;

    // lane holds leaky(Y) for k in [q*8, q*8+8)
    float ly[8];
    const float4* yvin = (const float4*)(Yio + (size_t)node * 32 + q * 8);
    {
        float4 t0 = yvin[0], t1 = yvin[1];
        ly[0] = leaky(t0.x); ly[1] = leaky(t0.y); ly[2] = leaky(t0.z); ly[3] = leaky(t0.w);
        ly[4] = leaky(t1.x); ly[5] = leaky(t1.y); ly[6] = leaky(t1.z); ly[7] = leaky(t1.w);
    }
    // h chunk: j in [q*16, q*16+16); k = ss*8 + kk via shfl
    float h[16];
    #pragma unroll
    for (int jj = 0; jj < 16; jj++) h[jj] = smb[q * 16 + jj];
    #pragma unroll
    for (int kk = 0; kk < 8; kk++) {
        #pragma unroll
        for (int ss = 0; ss < 4; ss++) {
            float v = __shfl(ly[kk], ss, 4);
            const float4* w = (const float4*)(sMW + (ss * 8 + kk) * 64 + q * 16);
            float4 a = w[0], b = w[1], c = w[2], d = w[3];
            ACC16(h, v, a, b, c, d)
        }
    }
    // residual
    float4* hp = (float4*)(H + (size_t)node * 64 + q * 16);
    #pragma unroll
    for (int c = 0; c < 4; c++) {
        float4 r = hp[c];
        h[4 * c] += r.x; h[4 * c + 1] += r.y; h[4 * c + 2] += r.z; h[4 * c + 3] += r.w;
    }
    // LN over quad
    float s = 0.f, s2 = 0.f;
    #pragma unroll
    for (int jj = 0; jj < 16; jj++) { s += h[jj]; s2 += h[jj] * h[jj]; }
    s  += __shfl_xor(s, 1, 4);  s  += __shfl_xor(s, 2, 4);
    s2 += __shfl_xor(s2, 1, 4); s2 += __shfl_xor(s2, 2, 4);
    float mu  = s * (1.f / 64.f);
    float var = s2 * (1.f / 64.f) - mu * mu;
    float rs  = rsqrtf(var + 1e-5f);

    float hn[16];
    #pragma unroll
    for (int jj = 0; jj < 16; jj++)
        hn[jj] = (h[jj] - mu) * rs * sg[q * 16 + jj] + sb[q * 16 + jj];
    #pragma unroll
    for (int c = 0; c < 4; c++)
        hp[c] = make_float4(hn[4 * c], hn[4 * c + 1], hn[4 * c + 2], hn[4 * c + 3]);

    // dual GEMM
    float aY[8], aZ[8];
    #pragma unroll
    for (int jj = 0; jj < 8; jj++) { aY[jj] = sby[q * 8 + jj]; aZ[jj] = 0.f; }
    #pragma unroll
    for (int kk = 0; kk < 16; kk++) {
        #pragma unroll
        for (int ss = 0; ss < 4; ss++) {
            float v = __shfl(hn[kk], ss, 4);
            int k = ss * 16 + kk;
            const float4* nw = (const float4*)(sNW + k * 32 + q * 8);
            const float4* ew = (const float4*)(sEW + k * 32 + q * 8);
            float4 a = nw[0], b = nw[1], c = ew[0], d = ew[1];
            ACC8(aY, v, a, b)
            ACC8(aZ, v, c, d)
        }
    }
    float4* yo = (float4*)(Yio + (size_t)node * 32 + q * 8);
    float4* zv = (float4*)(Z + (size_t)node * 32 + q * 8);
    yo[0] = make_float4(aY[0], aY[1], aY[2], aY[3]);
    yo[1] = make_float4(aY[4], aY[5], aY[6], aY[7]);
    zv[0] = make_float4(aZ[0], aZ[1], aZ[2], aZ[3]);
    zv[1] = make_float4(aZ[4], aZ[5], aZ[6], aZ[7]);
}

// ---------------------------------------------------------------------------
// Kernel C: mlp+residual (layer 3) then decoder.  Round-0 verbatim.
// ---------------------------------------------------------------------------
__global__ __launch_bounds__(256) void mlp_dec(
    const float* __restrict__ Y, const float* __restrict__ H,
    const float* __restrict__ mlpW, const float* __restrict__ mlp_b,
    const float* __restrict__ dW1, const float* __restrict__ db1,
    const float* __restrict__ dW2, const float* __restrict__ db2,
    float* __restrict__ out)
{
    __shared__ float sMW[32 * 64];
    __shared__ float smb[64];
    __shared__ float sW1t[24 * 65];   // [t][k] = dW1[k][t], stride 65 (bank spread)
    __shared__ float sb1[24];
    __shared__ float sW2[24 * 3];
    __shared__ float sb2v[3];
    for (int idx = threadIdx.x; idx < 32 * 64; idx += 256) sMW[idx] = mlpW[idx];
    for (int idx = threadIdx.x; idx < 64 * 24; idx += 256) {
        int k = idx / 24, t = idx % 24;
        sW1t[t * 65 + k] = dW1[idx];
    }
    if (threadIdx.x < 64) smb[threadIdx.x] = mlp_b[threadIdx.x];
    if (threadIdx.x < 24) sb1[threadIdx.x] = db1[threadIdx.x];
    if (threadIdx.x < 72) sW2[threadIdx.x] = dW2[threadIdx.x];
    if (threadIdx.x < 3)  sb2v[threadIdx.x] = db2[threadIdx.x];
    __syncthreads();

    int gid = blockIdx.x * 256 + threadIdx.x;
    int node = gid >> 2;
    int q = gid & 3;
    if (node >= N_NODES) return;

    float ly[8];
    const float4* yvin = (const float4*)(Y + (size_t)node * 32 + q * 8);
    {
        float4 t0 = yvin[0], t1 = yvin[1];
        ly[0] = leaky(t0.x); ly[1] = leaky(t0.y); ly[2] = leaky(t0.z); ly[3] = leaky(t0.w);
        ly[4] = leaky(t1.x); ly[5] = leaky(t1.y); ly[6] = leaky(t1.z); ly[7] = leaky(t1.w);
    }
    float h[16];
    #pragma unroll
    for (int jj = 0; jj < 16; jj++) h[jj] = smb[q * 16 + jj];
    #pragma unroll
    for (int kk = 0; kk < 8; kk++) {
        #pragma unroll
        for (int ss = 0; ss < 4; ss++) {
            float v = __shfl(ly[kk], ss, 4);
            const float4* w = (const float4*)(sMW + (ss * 8 + kk) * 64 + q * 16);
            float4 a = w[0], b = w[1], c = w[2], d = w[3];
            ACC16(h, v, a, b, c, d)
        }
    }
    const float4* hp = (const float4*)(H + (size_t)node * 64 + q * 16);
    #pragma unroll
    for (int c = 0; c < 4; c++) {
        float4 r = hp[c];
        h[4 * c] += r.x; h[4 * c + 1] += r.y; h[4 * c + 2] += r.z; h[4 * c + 3] += r.w;
    }
    // decoder hidden: lane q owns t in [q*6, q*6+6); k = ss*16+kk via shfl
    float hid[6];
    #pragma unroll
    for (int t = 0; t < 6; t++) hid[t] = sb1[q * 6 + t];
    #pragma unroll
    for (int kk = 0; kk < 16; kk++) {
        #pragma unroll
        for (int ss = 0; ss < 4; ss++) {
            float v = __shfl(h[kk], ss, 4);
            int k = ss * 16 + kk;
            #pragma unroll
            for (int t = 0; t < 6; t++)
                hid[t] += v * sW1t[(q * 6 + t) * 65 + k];
        }
    }
    float o0 = 0.f, o1 = 0.f, o2 = 0.f;
    #pragma unroll
    for (int t = 0; t < 6; t++) {
        float lt = leaky(hid[t]);
        int tg = q * 6 + t;
        o0 += lt * sW2[tg * 3 + 0];
        o1 += lt * sW2[tg * 3 + 1];
        o2 += lt * sW2[tg * 3 + 2];
    }
    o0 += __shfl_xor(o0, 1, 4); o0 += __shfl_xor(o0, 2, 4);
    o1 += __shfl_xor(o1, 1, 4); o1 += __shfl_xor(o1, 2, 4);
    o2 += __shfl_xor(o2, 1, 4); o2 += __shfl_xor(o2, 2, 4);
    if (q == 0) {
        float* op = out + (size_t)node * 3;
        op[0] = o0 + sb2v[0]; op[1] = o1 + sb2v[1]; op[2] = o2 + sb2v[2];
    }
}

// ---------------------------------------------------------------------------
extern "C" void kernel_launch(void* const* d_in, const int* in_sizes, int n_in,
                              void* d_out, int out_size, void* d_ws, size_t ws_size,
                              hipStream_t stream)
{
    const float* x      = (const float*)d_in[0];
    const int*   esrc   = (const int*)d_in[2];
    const int*   edst   = (const int*)d_in[3];
    const float* ew     = (const float*)d_in[4];
    const float* enc_W1 = (const float*)d_in[5];
    const float* enc_b1 = (const float*)d_in[6];
    const float* enc_W2 = (const float*)d_in[7];
    const float* enc_b2 = (const float*)d_in[8];
    const float* dec_W1 = (const float*)d_in[9];
    const float* dec_b1 = (const float*)d_in[10];
    const float* dec_W2 = (const float*)d_in[11];
    const float* dec_b2 = (const float*)d_in[12];
    const float* ln_g   = (const float*)d_in[13];
    const float* ln_b   = (const float*)d_in[14];
    const float* node_W = (const float*)d_in[15];
    const float* node_b = (const float*)d_in[16];
    const float* edge_W = (const float*)d_in[17];
    const float* edge_b = (const float*)d_in[18];
    const float* mlp_W  = (const float*)d_in[19];
    const float* mlp_b  = (const float*)d_in[20];

    // Workspace: floats H[N*64] | Y[N*32] | Z[N*32] | ep[E int2]
    //            ints counts[N] | offs[N+1] | cursor[N] | bsum | bscan
    float* H  = (float*)d_ws;
    float* Y  = H + (size_t)N_NODES * 64;
    float* Z  = Y + (size_t)N_NODES * 32;
    int2*  ep = (int2*)(Z + (size_t)N_NODES * 32);
    int* counts = (int*)(ep + N_EDGES);
    int* offs   = counts + N_NODES;          // N_NODES+1 entries
    int* cursor = offs + N_NODES + 1;
    int* bsum   = cursor + N_NODES;
    int* bscan  = bsum + NB1;
    // CSR-build scratch aliased over H (H is dead until enc_ln_gemm runs):
    int2* sP   = (int2*)H;
    int*  sD   = (int*)(sP + N_EDGES);
    int*  bcnt  = sD + N_EDGES;
    int*  boffs = bcnt + NBG;
    int*  bcur  = boffs + NBG + 1;

    const int nodeBlocks   = (N_NODES + 255) / 256;
    const int node4Blocks  = (N_NODES * 4 + 255) / 256;
    const int edgeBlocks   = (N_EDGES + 255) / 256;
    const int gatherBlocks = (N_NODES * 8 + 255) / 256;

    // --- CSR build (bucketed counting sort by dst) ---
    zero_counts<<<nodeBlocks, 256, 0, stream>>>(counts, bcnt);
    hist_kernel<<<edgeBlocks, 256, 0, stream>>>(edst, counts, bcnt);
    scan1_kernel<<<NB1, 256, 0, stream>>>(counts, offs, bsum);
    scan2_kernel<<<1, 128, 0, stream>>>(bsum, bscan);
    scan3_kernel<<<NB1, 256, 0, stream>>>(offs, cursor, bscan);
    bucket_scan<<<1, 256, 0, stream>>>(bcnt, boffs, bcur);
    bucket_fill<<<edgeBlocks, 256, 0, stream>>>(esrc, edst, ew, bcur, sP, sD);
    csr_fill<<<NB2, 256, 0, stream>>>(boffs, sP, sD, cursor, ep);

    // --- network ---
    enc_ln_gemm<<<node4Blocks, 256, 0, stream>>>(
        x, enc_W1, enc_b1, enc_W2, enc_b2,
        ln_g, ln_b, node_W, node_b, edge_W, edge_b, H, Y, Z);

    for (int l = 0; l < LAYERS - 1; l++) {
        gather_kernel<<<gatherBlocks, 256, 0, stream>>>(offs, ep, Z, Y);
        mlp_ln_gemm<<<node4Blocks, 256, 0, stream>>>(
            Y, H, Z,
            mlp_W + l * 32 * 64, mlp_b + l * 64,
            ln_g + (l + 1) * 64, ln_b + (l + 1) * 64,
            node_W + (l + 1) * 64 * 32, node_b + (l + 1) * 32,
            edge_W + (l + 1) * 64 * 32, edge_b + (l + 1) * 32);
    }
    gather_kernel<<<gatherBlocks, 256, 0, stream>>>(offs, ep, Z, Y);
    mlp_dec<<<node4Blocks, 256, 0, stream>>>(
        Y, H, mlp_W + 3 * 32 * 64, mlp_b + 3 * 64,
        dec_W1, dec_b1, dec_W2, dec_b2, (float*)d_out);
}

// Round 4
// 475.234 us; speedup vs baseline: 1.9394x; 1.3603x over previous
//
#include <hip/hip_runtime.h>

#define N_NODES 100000
#define N_EDGES 1200000
#define LAYERS 4
#define SLOPE 0.01f

// two-level zero-atomic counting sort
#define BUCKET_SHIFT 7
#define NB2 ((N_NODES + 127) >> 7)          // 782 buckets of 128 nodes
#define NBLK 128                            // scatter blocks
#define EPB (N_EDGES / NBLK)                // 9375 (exact)

__device__ __forceinline__ float leaky(float v) { return v >= 0.f ? v : SLOPE * v; }

#define ACC16(h, v, a, b, c, d) \
    h[0]  += v * a.x; h[1]  += v * a.y; h[2]  += v * a.z; h[3]  += v * a.w; \
    h[4]  += v * b.x; h[5]  += v * b.y; h[6]  += v * b.z; h[7]  += v * b.w; \
    h[8]  += v * c.x; h[9]  += v * c.y; h[10] += v * c.z; h[11] += v * c.w; \
    h[12] += v * d.x; h[13] += v * d.y; h[14] += v * d.z; h[15] += v * d.w;

#define ACC8(r, v, a, b) \
    r[0] += v * a.x; r[1] += v * a.y; r[2] += v * a.z; r[3] += v * a.w; \
    r[4] += v * b.x; r[5] += v * b.y; r[6] += v * b.z; r[7] += v * b.w;

// ---------------------------------------------------------------------------
// CSR build — zero global atomics.
// ---------------------------------------------------------------------------
// pass 1: per-block LDS histogram of dst-buckets, plain stores to Hg[blk][bkt]
__global__ __launch_bounds__(256) void hist_k(
    const int* __restrict__ dst, int* __restrict__ Hg)
{
    __shared__ int lh[NB2];
    for (int i = threadIdx.x; i < NB2; i += 256) lh[i] = 0;
    __syncthreads();
    int blk = blockIdx.x;
    int e1 = blk * EPB + EPB;
    for (int e = blk * EPB + threadIdx.x; e < e1; e += 256)
        atomicAdd(&lh[dst[e] >> BUCKET_SHIFT], 1);
    __syncthreads();
    for (int i = threadIdx.x; i < NB2; i += 256) Hg[blk * NB2 + i] = lh[i];
}

// pass 2a: per bucket, exclusive scan over the 128 block counts (in place)
__global__ __launch_bounds__(NBLK) void scan_blocks_k(
    int* __restrict__ Hg, int* __restrict__ T)
{
    __shared__ int s[NBLK];
    int b = blockIdx.x, t = threadIdx.x;
    int v = Hg[t * NB2 + b];
    s[t] = v; __syncthreads();
    for (int off = 1; off < NBLK; off <<= 1) {
        int y = (t >= off) ? s[t - off] : 0;
        __syncthreads();
        s[t] += y;
        __syncthreads();
    }
    Hg[t * NB2 + b] = s[t] - v;
    if (t == NBLK - 1) T[b] = s[t];
}

// pass 2b: scan bucket totals -> global bucket starts BS[0..NB2]
__global__ __launch_bounds__(256) void scan_T_k(
    const int* __restrict__ T, int* __restrict__ BS)
{
    __shared__ int s[256];
    int t = threadIdx.x;
    int beg = t * 4, end = beg + 4 > NB2 ? NB2 : beg + 4;
    int v[4]; int sum = 0;
    for (int i = beg, u = 0; i < end; i++, u++) { v[u] = sum; sum += T[i]; }
    s[t] = sum; __syncthreads();
    for (int off = 1; off < 256; off <<= 1) {
        int y = (t >= off) ? s[t - off] : 0;
        __syncthreads();
        s[t] += y;
        __syncthreads();
    }
    int excl = s[t] - sum;
    for (int i = beg, u = 0; i < end; i++, u++) BS[i] = excl + v[u];
    if (t == 0) BS[NB2] = N_EDGES;
}

// pass 3: scatter edges into exclusively-owned (blk,bucket) segments.
// pack: .x = src | ((d&127)<<17)  (src<2^17, 7-bit node-in-bucket), .y = w bits
__global__ __launch_bounds__(256) void scatter_k(
    const int* __restrict__ src, const int* __restrict__ dst,
    const float* __restrict__ w, const int* __restrict__ Hg,
    const int* __restrict__ BS, int2* __restrict__ sE)
{
    __shared__ int cur[NB2];
    int blk = blockIdx.x;
    for (int i = threadIdx.x; i < NB2; i += 256)
        cur[i] = BS[i] + Hg[blk * NB2 + i];
    __syncthreads();
    int e1 = blk * EPB + EPB;
    for (int e = blk * EPB + threadIdx.x; e < e1; e += 256) {
        int d = dst[e];
        int p = atomicAdd(&cur[d >> BUCKET_SHIFT], 1);
        sE[p] = make_int2(src[e] | ((d & 127) << 17), __float_as_int(w[e]));
    }
}

// pass 4: one block per bucket — LDS node-hist, block scan -> offs[] (node-major
// == bucket-major), then place edges into node-major ep via LDS cursors.
__global__ __launch_bounds__(256) void finalize_k(
    const int* __restrict__ BS, const int2* __restrict__ sE,
    int* __restrict__ offs, int2* __restrict__ ep)
{
    __shared__ int cnt[128];
    __shared__ int s[128];
    __shared__ int cur[128];
    int b = blockIdx.x, t = threadIdx.x;
    int s0 = BS[b], s1 = BS[b + 1];
    if (t < 128) cnt[t] = 0;
    __syncthreads();
    for (int i = s0 + t; i < s1; i += 256)
        atomicAdd(&cnt[(sE[i].x >> 17) & 127], 1);
    __syncthreads();
    int v = 0;
    if (t < 128) { v = cnt[t]; s[t] = v; }
    __syncthreads();
    for (int off = 1; off < 128; off <<= 1) {
        int y = (t >= off && t < 128) ? s[t - off] : 0;
        __syncthreads();
        if (t < 128) s[t] += y;
        __syncthreads();
    }
    if (t < 128) {
        int excl = s[t] - v;
        cur[t] = s0 + excl;
        int node = b * 128 + t;
        if (node < N_NODES) offs[node] = s0 + excl;
    }
    if (b == NB2 - 1 && t == 0) offs[N_NODES] = N_EDGES;
    __syncthreads();
    for (int i = s0 + t; i < s1; i += 256) {
        int2 e = sE[i];
        int p = atomicAdd(&cur[(e.x >> 17) & 127], 1);
        ep[p] = make_int2(e.x & 0x1FFFF, e.y);
    }
}

// ---------------------------------------------------------------------------
// Kernel A: encoder + LN(layer0) + dual GEMM(layer0).  4 lanes per node,
// stage-1 fused into stage-2 (round-3 form, verified).
// ---------------------------------------------------------------------------
__global__ __launch_bounds__(256) void enc_ln_gemm(
    const float* __restrict__ x,
    const float* __restrict__ W1, const float* __restrict__ b1,
    const float* __restrict__ W2, const float* __restrict__ b2,
    const float* __restrict__ ln_g, const float* __restrict__ ln_b,
    const float* __restrict__ nodeW, const float* __restrict__ node_b,
    const float* __restrict__ edgeW, const float* __restrict__ edge_b,
    float* __restrict__ H, float* __restrict__ Y, float* __restrict__ Z)
{
    __shared__ float sW1t[128 * 16];   // [k][i] = W1[i][k]
    __shared__ float sW2[128 * 64];
    __shared__ float sNW[64 * 32];
    __shared__ float sEW[64 * 32];
    __shared__ float sb1[128];
    __shared__ float sb2[64];
    __shared__ float sg[64], sb[64], sby[32];
    for (int idx = threadIdx.x; idx < 16 * 128; idx += 256) {
        int i = idx / 128, k = idx % 128;
        sW1t[k * 16 + i] = W1[idx];
    }
    for (int idx = threadIdx.x; idx < 128 * 64; idx += 256) sW2[idx] = W2[idx];
    for (int idx = threadIdx.x; idx < 64 * 32; idx += 256) {
        sNW[idx] = nodeW[idx];
        sEW[idx] = edgeW[idx];
    }
    if (threadIdx.x < 128) sb1[threadIdx.x] = b1[threadIdx.x];
    if (threadIdx.x < 64) {
        sb2[threadIdx.x] = b2[threadIdx.x];
        sg[threadIdx.x] = ln_g[threadIdx.x];
        sb[threadIdx.x] = ln_b[threadIdx.x];
    }
    if (threadIdx.x < 32) sby[threadIdx.x] = node_b[threadIdx.x] + edge_b[threadIdx.x];
    __syncthreads();

    int gid = blockIdx.x * 256 + threadIdx.x;
    int node = gid >> 2;
    int q = gid & 3;
    if (node >= N_NODES) return;

    float xi[16];
    const float4* xv = (const float4*)(x + (size_t)node * 16);
    #pragma unroll
    for (int i = 0; i < 4; i++) {
        float4 t = xv[i];
        xi[4 * i] = t.x; xi[4 * i + 1] = t.y; xi[4 * i + 2] = t.z; xi[4 * i + 3] = t.w;
    }

    float h[16];
    #pragma unroll
    for (int jj = 0; jj < 16; jj++) h[jj] = sb2[q * 16 + jj];
    #pragma unroll 4
    for (int kk = 0; kk < 32; kk++) {
        int t = kk * 4 + q;
        const float4* wv = (const float4*)(sW1t + t * 16);
        float4 w0 = wv[0], w1 = wv[1], w2 = wv[2], w3 = wv[3];
        float a = sb1[t];
        a += xi[0] * w0.x + xi[1] * w0.y + xi[2] * w0.z + xi[3] * w0.w;
        a += xi[4] * w1.x + xi[5] * w1.y + xi[6] * w1.z + xi[7] * w1.w;
        a += xi[8] * w2.x + xi[9] * w2.y + xi[10] * w2.z + xi[11] * w2.w;
        a += xi[12] * w3.x + xi[13] * w3.y + xi[14] * w3.z + xi[15] * w3.w;
        float hv = leaky(a);
        #pragma unroll
        for (int ss = 0; ss < 4; ss++) {
            float v = __shfl(hv, ss, 4);
            const float4* w = (const float4*)(sW2 + (kk * 4 + ss) * 64 + q * 16);
            float4 aa = w[0], bb = w[1], cc = w[2], dd = w[3];
            ACC16(h, v, aa, bb, cc, dd)
        }
    }

    // LN over quad
    float s = 0.f, s2 = 0.f;
    #pragma unroll
    for (int jj = 0; jj < 16; jj++) { s += h[jj]; s2 += h[jj] * h[jj]; }
    s  += __shfl_xor(s, 1, 4);  s  += __shfl_xor(s, 2, 4);
    s2 += __shfl_xor(s2, 1, 4); s2 += __shfl_xor(s2, 2, 4);
    float mu  = s * (1.f / 64.f);
    float var = s2 * (1.f / 64.f) - mu * mu;
    float rs  = rsqrtf(var + 1e-5f);

    float hn[16];
    #pragma unroll
    for (int jj = 0; jj < 16; jj++)
        hn[jj] = (h[jj] - mu) * rs * sg[q * 16 + jj] + sb[q * 16 + jj];

    float4* hs = (float4*)(H + (size_t)node * 64 + q * 16);
    #pragma unroll
    for (int c = 0; c < 4; c++)
        hs[c] = make_float4(hn[4 * c], hn[4 * c + 1], hn[4 * c + 2], hn[4 * c + 3]);

    // dual GEMM: lane owns cols [q*8, q*8+8); k = ss*16 + kk
    float aY[8], aZ[8];
    #pragma unroll
    for (int jj = 0; jj < 8; jj++) { aY[jj] = sby[q * 8 + jj]; aZ[jj] = 0.f; }
    #pragma unroll
    for (int kk = 0; kk < 16; kk++) {
        #pragma unroll
        for (int ss = 0; ss < 4; ss++) {
            float v = __shfl(hn[kk], ss, 4);
            int k = ss * 16 + kk;
            const float4* nw = (const float4*)(sNW + k * 32 + q * 8);
            const float4* ew = (const float4*)(sEW + k * 32 + q * 8);
            float4 a = nw[0], b = nw[1], c = ew[0], d = ew[1];
            ACC8(aY, v, a, b)
            ACC8(aZ, v, c, d)
        }
    }
    float4* yv = (float4*)(Y + (size_t)node * 32 + q * 8);
    float4* zv = (float4*)(Z + (size_t)node * 32 + q * 8);
    yv[0] = make_float4(aY[0], aY[1], aY[2], aY[3]);
    yv[1] = make_float4(aY[4], aY[5], aY[6], aY[7]);
    zv[0] = make_float4(aZ[0], aZ[1], aZ[2], aZ[3]);
    zv[1] = make_float4(aZ[4], aZ[5], aZ[6], aZ[7]);
}

// ---------------------------------------------------------------------------
// Gather: Y[n] += sum over incoming edges of w_e * Z[src_e]  (8 lanes/node)
// ---------------------------------------------------------------------------
__global__ __launch_bounds__(256) void gather_kernel(
    const int* __restrict__ offs, const int2* __restrict__ ep,
    const float* __restrict__ Z, float* __restrict__ Y)
{
    int gid = blockIdx.x * 256 + threadIdx.x;
    int node = gid >> 3;
    int lane = gid & 7;
    if (node >= N_NODES) return;
    int p0 = offs[node], p1 = offs[node + 1];
    float4 acc = make_float4(0.f, 0.f, 0.f, 0.f);
    const float4* Zv = (const float4*)Z;
    int p = p0;
    for (; p + 2 <= p1; p += 2) {
        int2 ea = ep[p];
        int2 eb = ep[p + 1];
        float wa = __int_as_float(ea.y);
        float wb = __int_as_float(eb.y);
        float4 za = Zv[(size_t)ea.x * 8 + lane];
        float4 zb = Zv[(size_t)eb.x * 8 + lane];
        acc.x += wa * za.x + wb * zb.x;
        acc.y += wa * za.y + wb * zb.y;
        acc.z += wa * za.z + wb * zb.z;
        acc.w += wa * za.w + wb * zb.w;
    }
    if (p < p1) {
        int2 ea = ep[p];
        float wa = __int_as_float(ea.y);
        float4 za = Zv[(size_t)ea.x * 8 + lane];
        acc.x += wa * za.x; acc.y += wa * za.y;
        acc.z += wa * za.z; acc.w += wa * za.w;
    }
    float4* yp = (float4*)(Y + (size_t)node * 32) + lane;
    float4 y = *yp;
    y.x += acc.x; y.y += acc.y; y.z += acc.z; y.w += acc.w;
    *yp = y;
}

// ---------------------------------------------------------------------------
// Kernel B: mlp+residual (layer l) then LN + dual GEMM (layer l+1).
// ---------------------------------------------------------------------------
__global__ __launch_bounds__(256) void mlp_ln_gemm(
    float* __restrict__ Yio, float* __restrict__ H, float* __restrict__ Z,
    const float* __restrict__ mlpW, const float* __restrict__ mlp_b,
    const float* __restrict__ ln_g, const float* __restrict__ ln_b,
    const float* __restrict__ nodeW, const float* __restrict__ node_b,
    const float* __restrict__ edgeW, const float* __restrict__ edge_b)
{
    __shared__ float sMW[32 * 64];
    __shared__ float sNW[64 * 32];
    __shared__ float sEW[64 * 32];
    __shared__ float smb[64], sg[64], sb[64], sby[32];
    for (int idx = threadIdx.x; idx < 32 * 64; idx += 256) sMW[idx] = mlpW[idx];
    for (int idx = threadIdx.x; idx < 64 * 32; idx += 256) {
        sNW[idx] = nodeW[idx];
        sEW[idx] = edgeW[idx];
    }
    if (threadIdx.x < 64) {
        smb[threadIdx.x] = mlp_b[threadIdx.x];
        sg[threadIdx.x] = ln_g[threadIdx.x];
        sb[threadIdx.x] = ln_b[threadIdx.x];
    }
    if (threadIdx.x < 32) sby[threadIdx.x] = node_b[threadIdx.x] + edge_b[threadIdx.x];
    __syncthreads();

    int gid = blockIdx.x * 256 + threadIdx.x;
    int node = gid >> 2;
    int q = gid & 3;
    if (node >= N_NODES) return;

    float ly[8];
    const float4* yvin = (const float4*)(Yio + (size_t)node * 32 + q * 8);
    {
        float4 t0 = yvin[0], t1 = yvin[1];
        ly[0] = leaky(t0.x); ly[1] = leaky(t0.y); ly[2] = leaky(t0.z); ly[3] = leaky(t0.w);
        ly[4] = leaky(t1.x); ly[5] = leaky(t1.y); ly[6] = leaky(t1.z); ly[7] = leaky(t1.w);
    }
    float h[16];
    #pragma unroll
    for (int jj = 0; jj < 16; jj++) h[jj] = smb[q * 16 + jj];
    #pragma unroll
    for (int kk = 0; kk < 8; kk++) {
        #pragma unroll
        for (int ss = 0; ss < 4; ss++) {
            float v = __shfl(ly[kk], ss, 4);
            const float4* w = (const float4*)(sMW + (ss * 8 + kk) * 64 + q * 16);
            float4 a = w[0], b = w[1], c = w[2], d = w[3];
            ACC16(h, v, a, b, c, d)
        }
    }
    float4* hp = (float4*)(H + (size_t)node * 64 + q * 16);
    #pragma unroll
    for (int c = 0; c < 4; c++) {
        float4 r = hp[c];
        h[4 * c] += r.x; h[4 * c + 1] += r.y; h[4 * c + 2] += r.z; h[4 * c + 3] += r.w;
    }
    float s = 0.f, s2 = 0.f;
    #pragma unroll
    for (int jj = 0; jj < 16; jj++) { s += h[jj]; s2 += h[jj] * h[jj]; }
    s  += __shfl_xor(s, 1, 4);  s  += __shfl_xor(s, 2, 4);
    s2 += __shfl_xor(s2, 1, 4); s2 += __shfl_xor(s2, 2, 4);
    float mu  = s * (1.f / 64.f);
    float var = s2 * (1.f / 64.f) - mu * mu;
    float rs  = rsqrtf(var + 1e-5f);

    float hn[16];
    #pragma unroll
    for (int jj = 0; jj < 16; jj++)
        hn[jj] = (h[jj] - mu) * rs * sg[q * 16 + jj] + sb[q * 16 + jj];
    #pragma unroll
    for (int c = 0; c < 4; c++)
        hp[c] = make_float4(hn[4 * c], hn[4 * c + 1], hn[4 * c + 2], hn[4 * c + 3]);

    float aY[8], aZ[8];
    #pragma unroll
    for (int jj = 0; jj < 8; jj++) { aY[jj] = sby[q * 8 + jj]; aZ[jj] = 0.f; }
    #pragma unroll
    for (int kk = 0; kk < 16; kk++) {
        #pragma unroll
        for (int ss = 0; ss < 4; ss++) {
            float v = __shfl(hn[kk], ss, 4);
            int k = ss * 16 + kk;
            const float4* nw = (const float4*)(sNW + k * 32 + q * 8);
            const float4* ew = (const float4*)(sEW + k * 32 + q * 8);
            float4 a = nw[0], b = nw[1], c = ew[0], d = ew[1];
            ACC8(aY, v, a, b)
            ACC8(aZ, v, c, d)
        }
    }
    float4* yo = (float4*)(Yio + (size_t)node * 32 + q * 8);
    float4* zv = (float4*)(Z + (size_t)node * 32 + q * 8);
    yo[0] = make_float4(aY[0], aY[1], aY[2], aY[3]);
    yo[1] = make_float4(aY[4], aY[5], aY[6], aY[7]);
    zv[0] = make_float4(aZ[0], aZ[1], aZ[2], aZ[3]);
    zv[1] = make_float4(aZ[4], aZ[5], aZ[6], aZ[7]);
}

// ---------------------------------------------------------------------------
// Kernel C: mlp+residual (layer 3) then decoder.
// ---------------------------------------------------------------------------
__global__ __launch_bounds__(256) void mlp_dec(
    const float* __restrict__ Y, const float* __restrict__ H,
    const float* __restrict__ mlpW, const float* __restrict__ mlp_b,
    const float* __restrict__ dW1, const float* __restrict__ db1,
    const float* __restrict__ dW2, const float* __restrict__ db2,
    float* __restrict__ out)
{
    __shared__ float sMW[32 * 64];
    __shared__ float smb[64];
    __shared__ float sW1t[24 * 65];
    __shared__ float sb1[24];
    __shared__ float sW2[24 * 3];
    __shared__ float sb2v[3];
    for (int idx = threadIdx.x; idx < 32 * 64; idx += 256) sMW[idx] = mlpW[idx];
    for (int idx = threadIdx.x; idx < 64 * 24; idx += 256) {
        int k = idx / 24, t = idx % 24;
        sW1t[t * 65 + k] = dW1[idx];
    }
    if (threadIdx.x < 64) smb[threadIdx.x] = mlp_b[threadIdx.x];
    if (threadIdx.x < 24) sb1[threadIdx.x] = db1[threadIdx.x];
    if (threadIdx.x < 72) sW2[threadIdx.x] = dW2[threadIdx.x];
    if (threadIdx.x < 3)  sb2v[threadIdx.x] = db2[threadIdx.x];
    __syncthreads();

    int gid = blockIdx.x * 256 + threadIdx.x;
    int node = gid >> 2;
    int q = gid & 3;
    if (node >= N_NODES) return;

    float ly[8];
    const float4* yvin = (const float4*)(Y + (size_t)node * 32 + q * 8);
    {
        float4 t0 = yvin[0], t1 = yvin[1];
        ly[0] = leaky(t0.x); ly[1] = leaky(t0.y); ly[2] = leaky(t0.z); ly[3] = leaky(t0.w);
        ly[4] = leaky(t1.x); ly[5] = leaky(t1.y); ly[6] = leaky(t1.z); ly[7] = leaky(t1.w);
    }
    float h[16];
    #pragma unroll
    for (int jj = 0; jj < 16; jj++) h[jj] = smb[q * 16 + jj];
    #pragma unroll
    for (int kk = 0; kk < 8; kk++) {
        #pragma unroll
        for (int ss = 0; ss < 4; ss++) {
            float v = __shfl(ly[kk], ss, 4);
            const float4* w = (const float4*)(sMW + (ss * 8 + kk) * 64 + q * 16);
            float4 a = w[0], b = w[1], c = w[2], d = w[3];
            ACC16(h, v, a, b, c, d)
        }
    }
    const float4* hp = (const float4*)(H + (size_t)node * 64 + q * 16);
    #pragma unroll
    for (int c = 0; c < 4; c++) {
        float4 r = hp[c];
        h[4 * c] += r.x; h[4 * c + 1] += r.y; h[4 * c + 2] += r.z; h[4 * c + 3] += r.w;
    }
    float hid[6];
    #pragma unroll
    for (int t = 0; t < 6; t++) hid[t] = sb1[q * 6 + t];
    #pragma unroll
    for (int kk = 0; kk < 16; kk++) {
        #pragma unroll
        for (int ss = 0; ss < 4; ss++) {
            float v = __shfl(h[kk], ss, 4);
            int k = ss * 16 + kk;
            #pragma unroll
            for (int t = 0; t < 6; t++)
                hid[t] += v * sW1t[(q * 6 + t) * 65 + k];
        }
    }
    float o0 = 0.f, o1 = 0.f, o2 = 0.f;
    #pragma unroll
    for (int t = 0; t < 6; t++) {
        float lt = leaky(hid[t]);
        int tg = q * 6 + t;
        o0 += lt * sW2[tg * 3 + 0];
        o1 += lt * sW2[tg * 3 + 1];
        o2 += lt * sW2[tg * 3 + 2];
    }
    o0 += __shfl_xor(o0, 1, 4); o0 += __shfl_xor(o0, 2, 4);
    o1 += __shfl_xor(o1, 1, 4); o1 += __shfl_xor(o1, 2, 4);
    o2 += __shfl_xor(o2, 1, 4); o2 += __shfl_xor(o2, 2, 4);
    if (q == 0) {
        float* op = out + (size_t)node * 3;
        op[0] = o0 + sb2v[0]; op[1] = o1 + sb2v[1]; op[2] = o2 + sb2v[2];
    }
}

// ---------------------------------------------------------------------------
extern "C" void kernel_launch(void* const* d_in, const int* in_sizes, int n_in,
                              void* d_out, int out_size, void* d_ws, size_t ws_size,
                              hipStream_t stream)
{
    const float* x      = (const float*)d_in[0];
    const int*   esrc   = (const int*)d_in[2];
    const int*   edst   = (const int*)d_in[3];
    const float* ew     = (const float*)d_in[4];
    const float* enc_W1 = (const float*)d_in[5];
    const float* enc_b1 = (const float*)d_in[6];
    const float* enc_W2 = (const float*)d_in[7];
    const float* enc_b2 = (const float*)d_in[8];
    const float* dec_W1 = (const float*)d_in[9];
    const float* dec_b1 = (const float*)d_in[10];
    const float* dec_W2 = (const float*)d_in[11];
    const float* dec_b2 = (const float*)d_in[12];
    const float* ln_g   = (const float*)d_in[13];
    const float* ln_b   = (const float*)d_in[14];
    const float* node_W = (const float*)d_in[15];
    const float* node_b = (const float*)d_in[16];
    const float* edge_W = (const float*)d_in[17];
    const float* edge_b = (const float*)d_in[18];
    const float* mlp_W  = (const float*)d_in[19];
    const float* mlp_b  = (const float*)d_in[20];

    // Workspace: floats H[N*64] | Y[N*32] | Z[N*32] | ep[E int2]
    //            | offs[N+1] | Hg[NBLK*NB2] | T[NB2] | BS[NB2+1]
    float* H  = (float*)d_ws;
    float* Y  = H + (size_t)N_NODES * 64;
    float* Z  = Y + (size_t)N_NODES * 32;
    int2*  ep = (int2*)(Z + (size_t)N_NODES * 32);
    int* offs = (int*)(ep + N_EDGES);        // N_NODES+1 entries
    int* Hg   = offs + N_NODES + 1;          // NBLK*NB2
    int* T    = Hg + NBLK * NB2;             // NB2
    int* BS   = T + NB2;                     // NB2+1
    // bucket-sorted edge scratch aliases H (dead until enc_ln_gemm)
    int2* sE  = (int2*)H;

    const int node4Blocks  = (N_NODES * 4 + 255) / 256;
    const int gatherBlocks = (N_NODES * 8 + 255) / 256;

    // --- CSR build (zero global atomics) ---
    hist_k<<<NBLK, 256, 0, stream>>>(edst, Hg);
    scan_blocks_k<<<NB2, NBLK, 0, stream>>>(Hg, T);
    scan_T_k<<<1, 256, 0, stream>>>(T, BS);
    scatter_k<<<NBLK, 256, 0, stream>>>(esrc, edst, ew, Hg, BS, sE);
    finalize_k<<<NB2, 256, 0, stream>>>(BS, sE, offs, ep);

    // --- network ---
    enc_ln_gemm<<<node4Blocks, 256, 0, stream>>>(
        x, enc_W1, enc_b1, enc_W2, enc_b2,
        ln_g, ln_b, node_W, node_b, edge_W, edge_b, H, Y, Z);

    for (int l = 0; l < LAYERS - 1; l++) {
        gather_kernel<<<gatherBlocks, 256, 0, stream>>>(offs, ep, Z, Y);
        mlp_ln_gemm<<<node4Blocks, 256, 0, stream>>>(
            Y, H, Z,
            mlp_W + l * 32 * 64, mlp_b + l * 64,
            ln_g + (l + 1) * 64, ln_b + (l + 1) * 64,
            node_W + (l + 1) * 64 * 32, node_b + (l + 1) * 32,
            edge_W + (l + 1) * 64 * 32, edge_b + (l + 1) * 32);
    }
    gather_kernel<<<gatherBlocks, 256, 0, stream>>>(offs, ep, Z, Y);
    mlp_dec<<<node4Blocks, 256, 0, stream>>>(
        Y, H, mlp_W + 3 * 32 * 64, mlp_b + 3 * 64,
        dec_W1, dec_b1, dec_W2, dec_b2, (float*)d_out);
}

// Round 5
// 461.473 us; speedup vs baseline: 1.9972x; 1.0298x over previous
//
#include <hip/hip_runtime.h>

#define N_NODES 100000
#define N_EDGES 1200000
#define LAYERS 4
#define SLOPE 0.01f

#define NPAIR (N_NODES / 2)                 // 50000 (N even)

// two-level zero-atomic counting sort
#define BUCKET_SHIFT 7
#define NB2 ((N_NODES + 127) >> 7)          // 782 buckets of 128 nodes
#define NBLK 128                            // scatter blocks
#define EPB (N_EDGES / NBLK)                // 9375 (exact)

__device__ __forceinline__ float leaky(float v) { return v >= 0.f ? v : SLOPE * v; }

#define ACC16(h, v, a, b, c, d) \
    h[0]  += v * a.x; h[1]  += v * a.y; h[2]  += v * a.z; h[3]  += v * a.w; \
    h[4]  += v * b.x; h[5]  += v * b.y; h[6]  += v * b.z; h[7]  += v * b.w; \
    h[8]  += v * c.x; h[9]  += v * c.y; h[10] += v * c.z; h[11] += v * c.w; \
    h[12] += v * d.x; h[13] += v * d.y; h[14] += v * d.z; h[15] += v * d.w;

#define ACC8(r, v, a, b) \
    r[0] += v * a.x; r[1] += v * a.y; r[2] += v * a.z; r[3] += v * a.w; \
    r[4] += v * b.x; r[5] += v * b.y; r[6] += v * b.z; r[7] += v * b.w;

// ---------------------------------------------------------------------------
// CSR build — zero global atomics (round-4 form, verified ~40 µs total).
// ---------------------------------------------------------------------------
__global__ __launch_bounds__(256) void hist_k(
    const int* __restrict__ dst, int* __restrict__ Hg)
{
    __shared__ int lh[NB2];
    for (int i = threadIdx.x; i < NB2; i += 256) lh[i] = 0;
    __syncthreads();
    int blk = blockIdx.x;
    int e1 = blk * EPB + EPB;
    for (int e = blk * EPB + threadIdx.x; e < e1; e += 256)
        atomicAdd(&lh[dst[e] >> BUCKET_SHIFT], 1);
    __syncthreads();
    for (int i = threadIdx.x; i < NB2; i += 256) Hg[blk * NB2 + i] = lh[i];
}

__global__ __launch_bounds__(NBLK) void scan_blocks_k(
    int* __restrict__ Hg, int* __restrict__ T)
{
    __shared__ int s[NBLK];
    int b = blockIdx.x, t = threadIdx.x;
    int v = Hg[t * NB2 + b];
    s[t] = v; __syncthreads();
    for (int off = 1; off < NBLK; off <<= 1) {
        int y = (t >= off) ? s[t - off] : 0;
        __syncthreads();
        s[t] += y;
        __syncthreads();
    }
    Hg[t * NB2 + b] = s[t] - v;
    if (t == NBLK - 1) T[b] = s[t];
}

__global__ __launch_bounds__(256) void scan_T_k(
    const int* __restrict__ T, int* __restrict__ BS)
{
    __shared__ int s[256];
    int t = threadIdx.x;
    int beg = t * 4, end = beg + 4 > NB2 ? NB2 : beg + 4;
    int v[4]; int sum = 0;
    for (int i = beg, u = 0; i < end; i++, u++) { v[u] = sum; sum += T[i]; }
    s[t] = sum; __syncthreads();
    for (int off = 1; off < 256; off <<= 1) {
        int y = (t >= off) ? s[t - off] : 0;
        __syncthreads();
        s[t] += y;
        __syncthreads();
    }
    int excl = s[t] - sum;
    for (int i = beg, u = 0; i < end; i++, u++) BS[i] = excl + v[u];
    if (t == 0) BS[NB2] = N_EDGES;
}

__global__ __launch_bounds__(256) void scatter_k(
    const int* __restrict__ src, const int* __restrict__ dst,
    const float* __restrict__ w, const int* __restrict__ Hg,
    const int* __restrict__ BS, int2* __restrict__ sE)
{
    __shared__ int cur[NB2];
    int blk = blockIdx.x;
    for (int i = threadIdx.x; i < NB2; i += 256)
        cur[i] = BS[i] + Hg[blk * NB2 + i];
    __syncthreads();
    int e1 = blk * EPB + EPB;
    for (int e = blk * EPB + threadIdx.x; e < e1; e += 256) {
        int d = dst[e];
        int p = atomicAdd(&cur[d >> BUCKET_SHIFT], 1);
        sE[p] = make_int2(src[e] | ((d & 127) << 17), __float_as_int(w[e]));
    }
}

__global__ __launch_bounds__(256) void finalize_k(
    const int* __restrict__ BS, const int2* __restrict__ sE,
    int* __restrict__ offs, int2* __restrict__ ep)
{
    __shared__ int cnt[128];
    __shared__ int s[128];
    __shared__ int cur[128];
    int b = blockIdx.x, t = threadIdx.x;
    int s0 = BS[b], s1 = BS[b + 1];
    if (t < 128) cnt[t] = 0;
    __syncthreads();
    for (int i = s0 + t; i < s1; i += 256)
        atomicAdd(&cnt[(sE[i].x >> 17) & 127], 1);
    __syncthreads();
    int v = 0;
    if (t < 128) { v = cnt[t]; s[t] = v; }
    __syncthreads();
    for (int off = 1; off < 128; off <<= 1) {
        int y = (t >= off && t < 128) ? s[t - off] : 0;
        __syncthreads();
        if (t < 128) s[t] += y;
        __syncthreads();
    }
    if (t < 128) {
        int excl = s[t] - v;
        cur[t] = s0 + excl;
        int node = b * 128 + t;
        if (node < N_NODES) offs[node] = s0 + excl;
    }
    if (b == NB2 - 1 && t == 0) offs[N_NODES] = N_EDGES;
    __syncthreads();
    for (int i = s0 + t; i < s1; i += 256) {
        int2 e = sE[i];
        int p = atomicAdd(&cur[(e.x >> 17) & 127], 1);
        ep[p] = make_int2(e.x & 0x1FFFF, e.y);
    }
}

// ---------------------------------------------------------------------------
// Kernel A: encoder + LN(layer0) + dual GEMM(layer0).
// 4 lanes x 2 nodes per thread, stage-1 fused (low live state), and
// __launch_bounds__(256,2): LDS (58.9KB) caps at 2 blocks/CU anyway, so the
// 256-VGPR budget is free — gives the allocator headroom to prefetch weight
// float4s across iterations (the round-1 2-node failure was the 128-VGPR
// default leaving zero headroom).  Each LDS weight read feeds 2 nodes.
// ---------------------------------------------------------------------------
__global__ __launch_bounds__(256, 2) void enc_ln_gemm(
    const float* __restrict__ x,
    const float* __restrict__ W1, const float* __restrict__ b1,
    const float* __restrict__ W2, const float* __restrict__ b2,
    const float* __restrict__ ln_g, const float* __restrict__ ln_b,
    const float* __restrict__ nodeW, const float* __restrict__ node_b,
    const float* __restrict__ edgeW, const float* __restrict__ edge_b,
    float* __restrict__ H, float* __restrict__ Y, float* __restrict__ Z)
{
    __shared__ float sW1t[128 * 16];   // [k][i] = W1[i][k]
    __shared__ float sW2[128 * 64];
    __shared__ float sNW[64 * 32];
    __shared__ float sEW[64 * 32];
    __shared__ float sb1[128];
    __shared__ float sb2[64];
    __shared__ float sg[64], sb[64], sby[32];
    for (int idx = threadIdx.x; idx < 16 * 128; idx += 256) {
        int i = idx / 128, k = idx % 128;
        sW1t[k * 16 + i] = W1[idx];
    }
    for (int idx = threadIdx.x; idx < 128 * 64; idx += 256) sW2[idx] = W2[idx];
    for (int idx = threadIdx.x; idx < 64 * 32; idx += 256) {
        sNW[idx] = nodeW[idx];
        sEW[idx] = edgeW[idx];
    }
    if (threadIdx.x < 128) sb1[threadIdx.x] = b1[threadIdx.x];
    if (threadIdx.x < 64) {
        sb2[threadIdx.x] = b2[threadIdx.x];
        sg[threadIdx.x] = ln_g[threadIdx.x];
        sb[threadIdx.x] = ln_b[threadIdx.x];
    }
    if (threadIdx.x < 32) sby[threadIdx.x] = node_b[threadIdx.x] + edge_b[threadIdx.x];
    __syncthreads();

    int base = blockIdx.x * 256 + threadIdx.x;
    int pair = base >> 2;
    int q = base & 3;
    if (pair >= NPAIR) return;
    int n0 = pair * 2, n1 = n0 + 1;

    float xi0[16], xi1[16];
    {
        const float4* xv0 = (const float4*)(x + (size_t)n0 * 16);
        const float4* xv1 = (const float4*)(x + (size_t)n1 * 16);
        #pragma unroll
        for (int i = 0; i < 4; i++) {
            float4 t = xv0[i];
            xi0[4 * i] = t.x; xi0[4 * i + 1] = t.y; xi0[4 * i + 2] = t.z; xi0[4 * i + 3] = t.w;
            float4 u = xv1[i];
            xi1[4 * i] = u.x; xi1[4 * i + 1] = u.y; xi1[4 * i + 2] = u.z; xi1[4 * i + 3] = u.w;
        }
    }

    // fused stage 1 + stage 2, both nodes share every weight read
    float h0[16], h1[16];
    #pragma unroll
    for (int jj = 0; jj < 16; jj++) { h0[jj] = sb2[q * 16 + jj]; h1[jj] = h0[jj]; }
    #pragma unroll 4
    for (int kk = 0; kk < 32; kk++) {
        int t = kk * 4 + q;
        const float4* wv = (const float4*)(sW1t + t * 16);
        float4 w0 = wv[0], w1 = wv[1], w2 = wv[2], w3 = wv[3];
        float a0 = sb1[t];
        a0 += xi0[0] * w0.x + xi0[1] * w0.y + xi0[2] * w0.z + xi0[3] * w0.w;
        a0 += xi0[4] * w1.x + xi0[5] * w1.y + xi0[6] * w1.z + xi0[7] * w1.w;
        a0 += xi0[8] * w2.x + xi0[9] * w2.y + xi0[10] * w2.z + xi0[11] * w2.w;
        a0 += xi0[12] * w3.x + xi0[13] * w3.y + xi0[14] * w3.z + xi0[15] * w3.w;
        float a1 = sb1[t];
        a1 += xi1[0] * w0.x + xi1[1] * w0.y + xi1[2] * w0.z + xi1[3] * w0.w;
        a1 += xi1[4] * w1.x + xi1[5] * w1.y + xi1[6] * w1.z + xi1[7] * w1.w;
        a1 += xi1[8] * w2.x + xi1[9] * w2.y + xi1[10] * w2.z + xi1[11] * w2.w;
        a1 += xi1[12] * w3.x + xi1[13] * w3.y + xi1[14] * w3.z + xi1[15] * w3.w;
        float hv0 = leaky(a0);
        float hv1 = leaky(a1);
        #pragma unroll
        for (int ss = 0; ss < 4; ss++) {
            float v0 = __shfl(hv0, ss, 4);
            float v1 = __shfl(hv1, ss, 4);
            const float4* w = (const float4*)(sW2 + (kk * 4 + ss) * 64 + q * 16);
            float4 aa = w[0], bb = w[1], cc = w[2], dd = w[3];
            ACC16(h0, v0, aa, bb, cc, dd)
            ACC16(h1, v1, aa, bb, cc, dd)
        }
    }

    // LN over quad (both nodes)
    float s0 = 0.f, e0 = 0.f, s1 = 0.f, e1 = 0.f;
    #pragma unroll
    for (int jj = 0; jj < 16; jj++) {
        s0 += h0[jj]; e0 += h0[jj] * h0[jj];
        s1 += h1[jj]; e1 += h1[jj] * h1[jj];
    }
    s0 += __shfl_xor(s0, 1, 4); s0 += __shfl_xor(s0, 2, 4);
    e0 += __shfl_xor(e0, 1, 4); e0 += __shfl_xor(e0, 2, 4);
    s1 += __shfl_xor(s1, 1, 4); s1 += __shfl_xor(s1, 2, 4);
    e1 += __shfl_xor(e1, 1, 4); e1 += __shfl_xor(e1, 2, 4);
    float mu0 = s0 * (1.f / 64.f);
    float va0 = e0 * (1.f / 64.f) - mu0 * mu0;
    float r0  = rsqrtf(va0 + 1e-5f);
    float mu1 = s1 * (1.f / 64.f);
    float va1 = e1 * (1.f / 64.f) - mu1 * mu1;
    float r1  = rsqrtf(va1 + 1e-5f);

    #pragma unroll
    for (int jj = 0; jj < 16; jj++) {
        float g = sg[q * 16 + jj], bb = sb[q * 16 + jj];
        h0[jj] = (h0[jj] - mu0) * r0 * g + bb;   // hn in place
        h1[jj] = (h1[jj] - mu1) * r1 * g + bb;
    }
    {
        float4* hs0 = (float4*)(H + (size_t)n0 * 64 + q * 16);
        float4* hs1 = (float4*)(H + (size_t)n1 * 64 + q * 16);
        #pragma unroll
        for (int c = 0; c < 4; c++) {
            hs0[c] = make_float4(h0[4 * c], h0[4 * c + 1], h0[4 * c + 2], h0[4 * c + 3]);
            hs1[c] = make_float4(h1[4 * c], h1[4 * c + 1], h1[4 * c + 2], h1[4 * c + 3]);
        }
    }

    // dual GEMM, both nodes share every weight read
    float aY0[8], aZ0[8], aY1[8], aZ1[8];
    #pragma unroll
    for (int jj = 0; jj < 8; jj++) {
        aY0[jj] = sby[q * 8 + jj]; aY1[jj] = aY0[jj];
        aZ0[jj] = 0.f; aZ1[jj] = 0.f;
    }
    #pragma unroll
    for (int kk = 0; kk < 16; kk++) {
        #pragma unroll
        for (int ss = 0; ss < 4; ss++) {
            float v0 = __shfl(h0[kk], ss, 4);
            float v1 = __shfl(h1[kk], ss, 4);
            int k = ss * 16 + kk;
            const float4* nw = (const float4*)(sNW + k * 32 + q * 8);
            const float4* ew = (const float4*)(sEW + k * 32 + q * 8);
            float4 a = nw[0], b = nw[1], c = ew[0], d = ew[1];
            ACC8(aY0, v0, a, b)
            ACC8(aZ0, v0, c, d)
            ACC8(aY1, v1, a, b)
            ACC8(aZ1, v1, c, d)
        }
    }
    float4* yv0 = (float4*)(Y + (size_t)n0 * 32 + q * 8);
    float4* zv0 = (float4*)(Z + (size_t)n0 * 32 + q * 8);
    float4* yv1 = (float4*)(Y + (size_t)n1 * 32 + q * 8);
    float4* zv1 = (float4*)(Z + (size_t)n1 * 32 + q * 8);
    yv0[0] = make_float4(aY0[0], aY0[1], aY0[2], aY0[3]);
    yv0[1] = make_float4(aY0[4], aY0[5], aY0[6], aY0[7]);
    zv0[0] = make_float4(aZ0[0], aZ0[1], aZ0[2], aZ0[3]);
    zv0[1] = make_float4(aZ0[4], aZ0[5], aZ0[6], aZ0[7]);
    yv1[0] = make_float4(aY1[0], aY1[1], aY1[2], aY1[3]);
    yv1[1] = make_float4(aY1[4], aY1[5], aY1[6], aY1[7]);
    zv1[0] = make_float4(aZ1[0], aZ1[1], aZ1[2], aZ1[3]);
    zv1[1] = make_float4(aZ1[4], aZ1[5], aZ1[6], aZ1[7]);
}

// ---------------------------------------------------------------------------
// Gather: Y[n] += sum over incoming edges of w_e * Z[src_e]  (8 lanes/node)
// unroll-by-4: keep 4 random Z-lines in flight per lane
// ---------------------------------------------------------------------------
__global__ __launch_bounds__(256) void gather_kernel(
    const int* __restrict__ offs, const int2* __restrict__ ep,
    const float* __restrict__ Z, float* __restrict__ Y)
{
    int gid = blockIdx.x * 256 + threadIdx.x;
    int node = gid >> 3;
    int lane = gid & 7;
    if (node >= N_NODES) return;
    int p0 = offs[node], p1 = offs[node + 1];
    float4 acc = make_float4(0.f, 0.f, 0.f, 0.f);
    const float4* Zv = (const float4*)Z;
    int p = p0;
    for (; p + 4 <= p1; p += 4) {
        int2 ea = ep[p];
        int2 eb = ep[p + 1];
        int2 ec = ep[p + 2];
        int2 ed = ep[p + 3];
        float4 za = Zv[(size_t)ea.x * 8 + lane];
        float4 zb = Zv[(size_t)eb.x * 8 + lane];
        float4 zc = Zv[(size_t)ec.x * 8 + lane];
        float4 zd = Zv[(size_t)ed.x * 8 + lane];
        float wa = __int_as_float(ea.y);
        float wb = __int_as_float(eb.y);
        float wc = __int_as_float(ec.y);
        float wd = __int_as_float(ed.y);
        acc.x += wa * za.x + wb * zb.x + wc * zc.x + wd * zd.x;
        acc.y += wa * za.y + wb * zb.y + wc * zc.y + wd * zd.y;
        acc.z += wa * za.z + wb * zb.z + wc * zc.z + wd * zd.z;
        acc.w += wa * za.w + wb * zb.w + wc * zc.w + wd * zd.w;
    }
    for (; p < p1; p++) {
        int2 ea = ep[p];
        float wa = __int_as_float(ea.y);
        float4 za = Zv[(size_t)ea.x * 8 + lane];
        acc.x += wa * za.x; acc.y += wa * za.y;
        acc.z += wa * za.z; acc.w += wa * za.w;
    }
    float4* yp = (float4*)(Y + (size_t)node * 32) + lane;
    float4 y = *yp;
    y.x += acc.x; y.y += acc.y; y.z += acc.z; y.w += acc.w;
    *yp = y;
}

// ---------------------------------------------------------------------------
// Kernel B: mlp+residual (layer l) then LN + dual GEMM (layer l+1).
// ---------------------------------------------------------------------------
__global__ __launch_bounds__(256) void mlp_ln_gemm(
    float* __restrict__ Yio, float* __restrict__ H, float* __restrict__ Z,
    const float* __restrict__ mlpW, const float* __restrict__ mlp_b,
    const float* __restrict__ ln_g, const float* __restrict__ ln_b,
    const float* __restrict__ nodeW, const float* __restrict__ node_b,
    const float* __restrict__ edgeW, const float* __restrict__ edge_b)
{
    __shared__ float sMW[32 * 64];
    __shared__ float sNW[64 * 32];
    __shared__ float sEW[64 * 32];
    __shared__ float smb[64], sg[64], sb[64], sby[32];
    for (int idx = threadIdx.x; idx < 32 * 64; idx += 256) sMW[idx] = mlpW[idx];
    for (int idx = threadIdx.x; idx < 64 * 32; idx += 256) {
        sNW[idx] = nodeW[idx];
        sEW[idx] = edgeW[idx];
    }
    if (threadIdx.x < 64) {
        smb[threadIdx.x] = mlp_b[threadIdx.x];
        sg[threadIdx.x] = ln_g[threadIdx.x];
        sb[threadIdx.x] = ln_b[threadIdx.x];
    }
    if (threadIdx.x < 32) sby[threadIdx.x] = node_b[threadIdx.x] + edge_b[threadIdx.x];
    __syncthreads();

    int gid = blockIdx.x * 256 + threadIdx.x;
    int node = gid >> 2;
    int q = gid & 3;
    if (node >= N_NODES) return;

    float ly[8];
    const float4* yvin = (const float4*)(Yio + (size_t)node * 32 + q * 8);
    {
        float4 t0 = yvin[0], t1 = yvin[1];
        ly[0] = leaky(t0.x); ly[1] = leaky(t0.y); ly[2] = leaky(t0.z); ly[3] = leaky(t0.w);
        ly[4] = leaky(t1.x); ly[5] = leaky(t1.y); ly[6] = leaky(t1.z); ly[7] = leaky(t1.w);
    }
    float h[16];
    #pragma unroll
    for (int jj = 0; jj < 16; jj++) h[jj] = smb[q * 16 + jj];
    #pragma unroll
    for (int kk = 0; kk < 8; kk++) {
        #pragma unroll
        for (int ss = 0; ss < 4; ss++) {
            float v = __shfl(ly[kk], ss, 4);
            const float4* w = (const float4*)(sMW + (ss * 8 + kk) * 64 + q * 16);
            float4 a = w[0], b = w[1], c = w[2], d = w[3];
            ACC16(h, v, a, b, c, d)
        }
    }
    float4* hp = (float4*)(H + (size_t)node * 64 + q * 16);
    #pragma unroll
    for (int c = 0; c < 4; c++) {
        float4 r = hp[c];
        h[4 * c] += r.x; h[4 * c + 1] += r.y; h[4 * c + 2] += r.z; h[4 * c + 3] += r.w;
    }
    float s = 0.f, s2 = 0.f;
    #pragma unroll
    for (int jj = 0; jj < 16; jj++) { s += h[jj]; s2 += h[jj] * h[jj]; }
    s  += __shfl_xor(s, 1, 4);  s  += __shfl_xor(s, 2, 4);
    s2 += __shfl_xor(s2, 1, 4); s2 += __shfl_xor(s2, 2, 4);
    float mu  = s * (1.f / 64.f);
    float var = s2 * (1.f / 64.f) - mu * mu;
    float rs  = rsqrtf(var + 1e-5f);

    float hn[16];
    #pragma unroll
    for (int jj = 0; jj < 16; jj++)
        hn[jj] = (h[jj] - mu) * rs * sg[q * 16 + jj] + sb[q * 16 + jj];
    #pragma unroll
    for (int c = 0; c < 4; c++)
        hp[c] = make_float4(hn[4 * c], hn[4 * c + 1], hn[4 * c + 2], hn[4 * c + 3]);

    float aY[8], aZ[8];
    #pragma unroll
    for (int jj = 0; jj < 8; jj++) { aY[jj] = sby[q * 8 + jj]; aZ[jj] = 0.f; }
    #pragma unroll
    for (int kk = 0; kk < 16; kk++) {
        #pragma unroll
        for (int ss = 0; ss < 4; ss++) {
            float v = __shfl(hn[kk], ss, 4);
            int k = ss * 16 + kk;
            const float4* nw = (const float4*)(sNW + k * 32 + q * 8);
            const float4* ew = (const float4*)(sEW + k * 32 + q * 8);
            float4 a = nw[0], b = nw[1], c = ew[0], d = ew[1];
            ACC8(aY, v, a, b)
            ACC8(aZ, v, c, d)
        }
    }
    float4* yo = (float4*)(Yio + (size_t)node * 32 + q * 8);
    float4* zv = (float4*)(Z + (size_t)node * 32 + q * 8);
    yo[0] = make_float4(aY[0], aY[1], aY[2], aY[3]);
    yo[1] = make_float4(aY[4], aY[5], aY[6], aY[7]);
    zv[0] = make_float4(aZ[0], aZ[1], aZ[2], aZ[3]);
    zv[1] = make_float4(aZ[4], aZ[5], aZ[6], aZ[7]);
}

// ---------------------------------------------------------------------------
// Kernel C: mlp+residual (layer 3) then decoder.
// ---------------------------------------------------------------------------
__global__ __launch_bounds__(256) void mlp_dec(
    const float* __restrict__ Y, const float* __restrict__ H,
    const float* __restrict__ mlpW, const float* __restrict__ mlp_b,
    const float* __restrict__ dW1, const float* __restrict__ db1,
    const float* __restrict__ dW2, const float* __restrict__ db2,
    float* __restrict__ out)
{
    __shared__ float sMW[32 * 64];
    __shared__ float smb[64];
    __shared__ float sW1t[24 * 65];
    __shared__ float sb1[24];
    __shared__ float sW2[24 * 3];
    __shared__ float sb2v[3];
    for (int idx = threadIdx.x; idx < 32 * 64; idx += 256) sMW[idx] = mlpW[idx];
    for (int idx = threadIdx.x; idx < 64 * 24; idx += 256) {
        int k = idx / 24, t = idx % 24;
        sW1t[t * 65 + k] = dW1[idx];
    }
    if (threadIdx.x < 64) smb[threadIdx.x] = mlp_b[threadIdx.x];
    if (threadIdx.x < 24) sb1[threadIdx.x] = db1[threadIdx.x];
    if (threadIdx.x < 72) sW2[threadIdx.x] = dW2[threadIdx.x];
    if (threadIdx.x < 3)  sb2v[threadIdx.x] = db2[threadIdx.x];
    __syncthreads();

    int gid = blockIdx.x * 256 + threadIdx.x;
    int node = gid >> 2;
    int q = gid & 3;
    if (node >= N_NODES) return;

    float ly[8];
    const float4* yvin = (const float4*)(Y + (size_t)node * 32 + q * 8);
    {
        float4 t0 = yvin[0], t1 = yvin[1];
        ly[0] = leaky(t0.x); ly[1] = leaky(t0.y); ly[2] = leaky(t0.z); ly[3] = leaky(t0.w);
        ly[4] = leaky(t1.x); ly[5] = leaky(t1.y); ly[6] = leaky(t1.z); ly[7] = leaky(t1.w);
    }
    float h[16];
    #pragma unroll
    for (int jj = 0; jj < 16; jj++) h[jj] = smb[q * 16 + jj];
    #pragma unroll
    for (int kk = 0; kk < 8; kk++) {
        #pragma unroll
        for (int ss = 0; ss < 4; ss++) {
            float v = __shfl(ly[kk], ss, 4);
            const float4* w = (const float4*)(sMW + (ss * 8 + kk) * 64 + q * 16);
            float4 a = w[0], b = w[1], c = w[2], d = w[3];
            ACC16(h, v, a, b, c, d)
        }
    }
    const float4* hp = (const float4*)(H + (size_t)node * 64 + q * 16);
    #pragma unroll
    for (int c = 0; c < 4; c++) {
        float4 r = hp[c];
        h[4 * c] += r.x; h[4 * c + 1] += r.y; h[4 * c + 2] += r.z; h[4 * c + 3] += r.w;
    }
    float hid[6];
    #pragma unroll
    for (int t = 0; t < 6; t++) hid[t] = sb1[q * 6 + t];
    #pragma unroll
    for (int kk = 0; kk < 16; kk++) {
        #pragma unroll
        for (int ss = 0; ss < 4; ss++) {
            float v = __shfl(h[kk], ss, 4);
            int k = ss * 16 + kk;
            #pragma unroll
            for (int t = 0; t < 6; t++)
                hid[t] += v * sW1t[(q * 6 + t) * 65 + k];
        }
    }
    float o0 = 0.f, o1 = 0.f, o2 = 0.f;
    #pragma unroll
    for (int t = 0; t < 6; t++) {
        float lt = leaky(hid[t]);
        int tg = q * 6 + t;
        o0 += lt * sW2[tg * 3 + 0];
        o1 += lt * sW2[tg * 3 + 1];
        o2 += lt * sW2[tg * 3 + 2];
    }
    o0 += __shfl_xor(o0, 1, 4); o0 += __shfl_xor(o0, 2, 4);
    o1 += __shfl_xor(o1, 1, 4); o1 += __shfl_xor(o1, 2, 4);
    o2 += __shfl_xor(o2, 1, 4); o2 += __shfl_xor(o2, 2, 4);
    if (q == 0) {
        float* op = out + (size_t)node * 3;
        op[0] = o0 + sb2v[0]; op[1] = o1 + sb2v[1]; op[2] = o2 + sb2v[2];
    }
}

// ---------------------------------------------------------------------------
extern "C" void kernel_launch(void* const* d_in, const int* in_sizes, int n_in,
                              void* d_out, int out_size, void* d_ws, size_t ws_size,
                              hipStream_t stream)
{
    const float* x      = (const float*)d_in[0];
    const int*   esrc   = (const int*)d_in[2];
    const int*   edst   = (const int*)d_in[3];
    const float* ew     = (const float*)d_in[4];
    const float* enc_W1 = (const float*)d_in[5];
    const float* enc_b1 = (const float*)d_in[6];
    const float* enc_W2 = (const float*)d_in[7];
    const float* enc_b2 = (const float*)d_in[8];
    const float* dec_W1 = (const float*)d_in[9];
    const float* dec_b1 = (const float*)d_in[10];
    const float* dec_W2 = (const float*)d_in[11];
    const float* dec_b2 = (const float*)d_in[12];
    const float* ln_g   = (const float*)d_in[13];
    const float* ln_b   = (const float*)d_in[14];
    const float* node_W = (const float*)d_in[15];
    const float* node_b = (const float*)d_in[16];
    const float* edge_W = (const float*)d_in[17];
    const float* edge_b = (const float*)d_in[18];
    const float* mlp_W  = (const float*)d_in[19];
    const float* mlp_b  = (const float*)d_in[20];

    // Workspace: floats H[N*64] | Y[N*32] | Z[N*32] | ep[E int2]
    //            | offs[N+1] | Hg[NBLK*NB2] | T[NB2] | BS[NB2+1]
    float* H  = (float*)d_ws;
    float* Y  = H + (size_t)N_NODES * 64;
    float* Z  = Y + (size_t)N_NODES * 32;
    int2*  ep = (int2*)(Z + (size_t)N_NODES * 32);
    int* offs = (int*)(ep + N_EDGES);        // N_NODES+1 entries
    int* Hg   = offs + N_NODES + 1;          // NBLK*NB2
    int* T    = Hg + NBLK * NB2;             // NB2
    int* BS   = T + NB2;                     // NB2+1
    // bucket-sorted edge scratch aliases H (dead until enc_ln_gemm)
    int2* sE  = (int2*)H;

    const int pairBlocks   = (NPAIR * 4 + 255) / 256;
    const int node4Blocks  = (N_NODES * 4 + 255) / 256;
    const int gatherBlocks = (N_NODES * 8 + 255) / 256;

    // --- CSR build (zero global atomics) ---
    hist_k<<<NBLK, 256, 0, stream>>>(edst, Hg);
    scan_blocks_k<<<NB2, NBLK, 0, stream>>>(Hg, T);
    scan_T_k<<<1, 256, 0, stream>>>(T, BS);
    scatter_k<<<NBLK, 256, 0, stream>>>(esrc, edst, ew, Hg, BS, sE);
    finalize_k<<<NB2, 256, 0, stream>>>(BS, sE, offs, ep);

    // --- network ---
    enc_ln_gemm<<<pairBlocks, 256, 0, stream>>>(
        x, enc_W1, enc_b1, enc_W2, enc_b2,
        ln_g, ln_b, node_W, node_b, edge_W, edge_b, H, Y, Z);

    for (int l = 0; l < LAYERS - 1; l++) {
        gather_kernel<<<gatherBlocks, 256, 0, stream>>>(offs, ep, Z, Y);
        mlp_ln_gemm<<<node4Blocks, 256, 0, stream>>>(
            Y, H, Z,
            mlp_W + l * 32 * 64, mlp_b + l * 64,
            ln_g + (l + 1) * 64, ln_b + (l + 1) * 64,
            node_W + (l + 1) * 64 * 32, node_b + (l + 1) * 32,
            edge_W + (l + 1) * 64 * 32, edge_b + (l + 1) * 32);
    }
    gather_kernel<<<gatherBlocks, 256, 0, stream>>>(offs, ep, Z, Y);
    mlp_dec<<<node4Blocks, 256, 0, stream>>>(
        Y, H, mlp_W + 3 * 32 * 64, mlp_b + 3 * 64,
        dec_W1, dec_b1, dec_W2, dec_b2, (float*)d_out);
}